// Round 12
// baseline (1043.248 us; speedup 1.0000x reference)
//
#include <hip/hip_runtime.h>

#define MROWS 4096
#define DDIM  512
#define FFND  2048
#define NLAY  4
#define KCB   16384
#define LN_EPS 1e-5f

typedef unsigned short u16;
typedef _Float16 half8 __attribute__((ext_vector_type(8)));
typedef float f32x4 __attribute__((ext_vector_type(4)));

// ---- workspace layout (byte offsets) ----
#define B_X    0ULL
#define B_Q    8388608ULL
#define B_K    16777216ULL
#define B_V    25165824ULL
#define B_CT   33554432ULL
#define B_TMP  41943040ULL
#define B_H    8388608ULL
#define B_CBH  8388608ULL
#define B_CBL  25165824ULL
#define B_ZEH  41943040ULL
#define B_ZEL  46137344ULL
#define B_ZN   50331648ULL
#define B_CN   50348032ULL
#define B_RL   50413568ULL
#define B_BEST 50429952ULL
#define B_HIST 50462720ULL
#define B_WT   50528256ULL

// fp16 2-way split: x = h + l + eps, |eps| <= 2^-22|x|.
__device__ __forceinline__ void splitf16(float x, u16& h, u16& l) {
  _Float16 hh = (_Float16)x;          // RNE
  float r = x - (float)hh;            // exact
  _Float16 ll = (_Float16)r;          // RNE
  h = *(u16*)&hh; l = *(u16*)&ll;
}

__device__ __forceinline__ unsigned int fkey(float f) {
  unsigned int u = __float_as_uint(f);
  return (u & 0x80000000u) ? ~u : (u | 0x80000000u);
}

// ===================== 64x128 split-fp16 MFMA GEMM body (round-6/8 proven; qkv) =====================
template<int EPI>
__device__ __forceinline__ void gemm64_body(const float* __restrict__ Af,
    const u16* __restrict__ Bhi, const u16* __restrict__ Blo,
    const float* __restrict__ bias, float* __restrict__ C, int Kd, int N) {
  __shared__ __align__(16) u16 As[2][2048];   // 64 rows x 32 k
  __shared__ __align__(16) u16 Bs[2][4096];   // 128 rows x 32 k
  const int t = threadIdx.x;
  const int w = t >> 6, l = t & 63;
  const int lr = l & 15, lg = l >> 4;
  const int m0 = blockIdx.y * 64, n0 = blockIdx.x * 128;

  f32x4 acc[4][2];
  const f32x4 zf = {0.f, 0.f, 0.f, 0.f};
#pragma unroll
  for (int mi = 0; mi < 4; ++mi)
#pragma unroll
    for (int ni = 0; ni < 2; ++ni) acc[mi][ni] = zf;

  for (int k0 = 0; k0 < Kd; k0 += 32) {
#pragma unroll
    for (int pl = 0; pl < 2; ++pl) {
      const u16* gp = pl ? Blo : Bhi;
      u16* lb = &Bs[pl][0];
#pragma unroll
      for (int i = 0; i < 2; ++i) {
        int ob = w * 2048 + i * 1024;
        int o = ob + l * 16;
        int r = o >> 6;
        int pc = (o >> 4) & 3;
        int c = pc ^ ((r + (r >> 2)) & 3);
        const u16* g = gp + (size_t)(n0 + r) * Kd + k0 + c * 8;
        __builtin_amdgcn_global_load_lds(
            (const __attribute__((address_space(1))) unsigned int*)(const void*)g,
            (__attribute__((address_space(3))) unsigned int*)(void*)(lb + (ob >> 1)), 16, 0, 0);
      }
    }
#pragma unroll
    for (int p = 0; p < 2; ++p) {
      int e = p * 256 + t;
      int r = e >> 3, kc = (e & 7) * 4;
      float4 a = *(const float4*)(Af + (size_t)(m0 + r) * Kd + k0 + kc);
      u16 h0, h1, h2, h3, q0, q1, q2, q3;
      splitf16(a.x, h0, q0); splitf16(a.y, h1, q1); splitf16(a.z, h2, q2); splitf16(a.w, h3, q3);
      int idx = r * 32 + ((((kc >> 3) ^ ((r + (r >> 2)) & 3))) << 3) + (kc & 7);
      *(uint2*)&As[0][idx] = make_uint2((unsigned)h0 | ((unsigned)h1 << 16), (unsigned)h2 | ((unsigned)h3 << 16));
      *(uint2*)&As[1][idx] = make_uint2((unsigned)q0 | ((unsigned)q1 << 16), (unsigned)q2 | ((unsigned)q3 << 16));
    }
    __syncthreads();
    half8 ah[4], al[4], bh2[2], bl2[2];
#pragma unroll
    for (int mi = 0; mi < 4; ++mi) {
      int r = mi * 16 + lr;
      int idx = r * 32 + ((lg ^ ((r + (r >> 2)) & 3)) << 3);
      ah[mi] = *(const half8*)&As[0][idx];
      al[mi] = *(const half8*)&As[1][idx];
    }
#pragma unroll
    for (int ni = 0; ni < 2; ++ni) {
      int r = w * 32 + ni * 16 + lr;
      int idx = r * 32 + ((lg ^ ((r + (r >> 2)) & 3)) << 3);
      bh2[ni] = *(const half8*)&Bs[0][idx];
      bl2[ni] = *(const half8*)&Bs[1][idx];
    }
#pragma unroll
    for (int mi = 0; mi < 4; ++mi)
#pragma unroll
      for (int ni = 0; ni < 2; ++ni) {
        acc[mi][ni] = __builtin_amdgcn_mfma_f32_16x16x32_f16(ah[mi], bh2[ni], acc[mi][ni], 0, 0, 0);
        acc[mi][ni] = __builtin_amdgcn_mfma_f32_16x16x32_f16(ah[mi], bl2[ni], acc[mi][ni], 0, 0, 0);
        acc[mi][ni] = __builtin_amdgcn_mfma_f32_16x16x32_f16(al[mi], bh2[ni], acc[mi][ni], 0, 0, 0);
      }
    __syncthreads();
  }

  float bv[2];
#pragma unroll
  for (int ni = 0; ni < 2; ++ni) bv[ni] = bias[n0 + w * 32 + ni * 16 + lr];
#pragma unroll
  for (int mi = 0; mi < 4; ++mi)
#pragma unroll
    for (int j = 0; j < 4; ++j) {
      int m = m0 + mi * 16 + lg * 4 + j;
#pragma unroll
      for (int ni = 0; ni < 2; ++ni) {
        int n = n0 + w * 32 + ni * 16 + lr;
        float o = acc[mi][ni][j] + bv[ni];
        if (EPI == 1) o = fmaxf(o, 0.f);
        C[(size_t)m * N + n] = o;
      }
    }
}

__global__ __launch_bounds__(256) void qkv_enc(const float* __restrict__ Af,
    const u16* __restrict__ wt, const float* __restrict__ bq, const float* __restrict__ bk,
    const float* __restrict__ bv_, float* __restrict__ Cq) {
  const int z = blockIdx.z;
  const u16* Bhi = wt + (size_t)z * 524288;
  const u16* Blo = Bhi + 262144;
  const float* bias = (z == 0) ? bq : (z == 1) ? bk : bv_;
  float* C = Cq + (size_t)z * 2097152;
  gemm64_body<0>(Af, Bhi, Blo, bias, C, 512, 512);
}

// ===================== pipelined 64x128 GEMM (Wo, FFN2: 1 block/CU, stage-ahead) =====================
// vq256-style: issue loads for step k+1 BEFORE compute(k); drain vmcnt+lgkm AFTER; single barrier.
template<int EPI>
__global__ __launch_bounds__(256) void gemm_enc_p(const float* __restrict__ Af,
    const u16* __restrict__ Bhi, const u16* __restrict__ Blo,
    const float* __restrict__ bias, float* __restrict__ C, int Kd, int N) {
  __shared__ __align__(16) u16 As[2][2][2048];   // [buf][plane][64*32]
  __shared__ __align__(16) u16 Bs[2][2][4096];   // [buf][plane][128*32]
  const int t = threadIdx.x;
  const int w = t >> 6, l = t & 63;
  const int lr = l & 15, lg = l >> 4;
  const int m0 = blockIdx.y * 64, n0 = blockIdx.x * 128;

  f32x4 acc[4][2];
  const f32x4 zf = {0.f, 0.f, 0.f, 0.f};
#pragma unroll
  for (int mi = 0; mi < 4; ++mi)
#pragma unroll
    for (int ni = 0; ni < 2; ++ni) acc[mi][ni] = zf;

  // B staging geometry (2 chunks/wave/plane)
  int b_ob[2], b_r[2], b_c[2];
#pragma unroll
  for (int i = 0; i < 2; ++i) {
    int ob = w * 2048 + i * 1024;
    int o = ob + l * 16;
    int r = o >> 6;
    int c = ((o >> 4) & 3) ^ ((r + (r >> 2)) & 3);
    b_ob[i] = ob; b_r[i] = r; b_c[i] = c;
  }
  // A geometry (2 float4/thread)
  int a_r[2], a_kc[2], a_idx[2];
#pragma unroll
  for (int p = 0; p < 2; ++p) {
    int e = p * 256 + t;
    a_r[p] = e >> 3; a_kc[p] = (e & 7) * 4;
    a_idx[p] = a_r[p] * 32 + ((((a_kc[p] >> 3) ^ ((a_r[p] + (a_r[p] >> 2)) & 3))) << 3) + (a_kc[p] & 7);
  }

#define GP_STAGE_B(buf, k0)                                                             \
  { _Pragma("unroll")                                                                   \
    for (int pl = 0; pl < 2; ++pl) {                                                    \
      const u16* gp = pl ? Blo : Bhi;                                                   \
      _Pragma("unroll")                                                                 \
      for (int i = 0; i < 2; ++i) {                                                     \
        const u16* g = gp + (size_t)(n0 + b_r[i]) * Kd + (k0) + b_c[i] * 8;             \
        __builtin_amdgcn_global_load_lds(                                               \
            (const __attribute__((address_space(1))) unsigned int*)(const void*)g,      \
            (__attribute__((address_space(3))) unsigned int*)(void*)(&Bs[buf][pl][b_ob[i] >> 1]), 16, 0, 0); \
      } } }

#define GP_LOAD_A(ar, k0)                                                               \
  { _Pragma("unroll")                                                                   \
    for (int p = 0; p < 2; ++p)                                                         \
      ar[p] = *(const float4*)(Af + (size_t)(m0 + a_r[p]) * Kd + (k0) + a_kc[p]); }

#define GP_WRITE_A(buf, ar)                                                             \
  { _Pragma("unroll")                                                                   \
    for (int p = 0; p < 2; ++p) {                                                       \
      u16 h0, h1, h2, h3, q0, q1, q2, q3;                                               \
      splitf16(ar[p].x, h0, q0); splitf16(ar[p].y, h1, q1);                             \
      splitf16(ar[p].z, h2, q2); splitf16(ar[p].w, h3, q3);                             \
      *(uint2*)&As[buf][0][a_idx[p]] = make_uint2((unsigned)h0 | ((unsigned)h1 << 16), (unsigned)h2 | ((unsigned)h3 << 16)); \
      *(uint2*)&As[buf][1][a_idx[p]] = make_uint2((unsigned)q0 | ((unsigned)q1 << 16), (unsigned)q2 | ((unsigned)q3 << 16)); \
    } }

  {
    float4 a0[2];
    GP_LOAD_A(a0, 0);
    GP_STAGE_B(0, 0);
    GP_WRITE_A(0, a0);
  }
  asm volatile("s_waitcnt vmcnt(0) lgkmcnt(0)" ::: "memory");
  __builtin_amdgcn_s_barrier();

  int cur = 0;
  const int nk = Kd >> 5;
#pragma unroll 1
  for (int ks = 0; ks < nk; ++ks) {
    // fragment reads from buf[cur]
    half8 ah[4], al[4], bh2[2], bl2[2];
#pragma unroll
    for (int mi = 0; mi < 4; ++mi) {
      int r = mi * 16 + lr;
      int idx = r * 32 + ((lg ^ ((r + (r >> 2)) & 3)) << 3);
      ah[mi] = *(const half8*)&As[cur][0][idx];
      al[mi] = *(const half8*)&As[cur][1][idx];
    }
#pragma unroll
    for (int ni = 0; ni < 2; ++ni) {
      int r = w * 32 + ni * 16 + lr;
      int idx = r * 32 + ((lg ^ ((r + (r >> 2)) & 3)) << 3);
      bh2[ni] = *(const half8*)&Bs[cur][0][idx];
      bl2[ni] = *(const half8*)&Bs[cur][1][idx];
    }
    // issue next-step loads (hide under MFMA)
    float4 an[2];
    if (ks + 1 < nk) {
      GP_LOAD_A(an, (ks + 1) * 32);
      GP_STAGE_B(cur ^ 1, (ks + 1) * 32);
    }
#pragma unroll
    for (int mi = 0; mi < 4; ++mi)
#pragma unroll
      for (int ni = 0; ni < 2; ++ni) {
        acc[mi][ni] = __builtin_amdgcn_mfma_f32_16x16x32_f16(ah[mi], bh2[ni], acc[mi][ni], 0, 0, 0);
        acc[mi][ni] = __builtin_amdgcn_mfma_f32_16x16x32_f16(ah[mi], bl2[ni], acc[mi][ni], 0, 0, 0);
        acc[mi][ni] = __builtin_amdgcn_mfma_f32_16x16x32_f16(al[mi], bh2[ni], acc[mi][ni], 0, 0, 0);
      }
    if (ks + 1 < nk) GP_WRITE_A(cur ^ 1, an);
    asm volatile("s_waitcnt vmcnt(0) lgkmcnt(0)" ::: "memory");
    __builtin_amdgcn_s_barrier();
    cur ^= 1;
  }

  float bv[2];
#pragma unroll
  for (int ni = 0; ni < 2; ++ni) bv[ni] = bias[n0 + w * 32 + ni * 16 + lr];
#pragma unroll
  for (int mi = 0; mi < 4; ++mi)
#pragma unroll
    for (int j = 0; j < 4; ++j) {
      int m = m0 + mi * 16 + lg * 4 + j;
#pragma unroll
      for (int ni = 0; ni < 2; ++ni) {
        int n = n0 + w * 32 + ni * 16 + lr;
        float o = acc[mi][ni][j] + bv[ni];
        if (EPI == 1) o = fmaxf(o, 0.f);
        C[(size_t)m * N + n] = o;
      }
    }
#undef GP_STAGE_B
#undef GP_LOAD_A
#undef GP_WRITE_A
}

// ===================== 128x128 split-fp16 MFMA GEMM (FFN1) =====================
template<int EPI>
__global__ __launch_bounds__(256) void gemm128(const float* __restrict__ Af,
    const u16* __restrict__ Bhi, const u16* __restrict__ Blo,
    const float* __restrict__ bias, float* __restrict__ C, int Kd, int N) {
  __shared__ __align__(16) u16 As[2][4096];
  __shared__ __align__(16) u16 Bs[2][4096];
  const int t = threadIdx.x;
  const int w = t >> 6, l = t & 63;
  const int lr = l & 15, lg = l >> 4;
  const int wr = w >> 1, wc = w & 1;
  const int m0 = blockIdx.y * 128, n0 = blockIdx.x * 128;

  f32x4 acc[4][4];
  const f32x4 zf = {0.f, 0.f, 0.f, 0.f};
#pragma unroll
  for (int mi = 0; mi < 4; ++mi)
#pragma unroll
    for (int ni = 0; ni < 4; ++ni) acc[mi][ni] = zf;

  for (int k0 = 0; k0 < Kd; k0 += 32) {
#pragma unroll
    for (int pl = 0; pl < 2; ++pl) {
      const u16* gp = pl ? Blo : Bhi;
      u16* lb = &Bs[pl][0];
#pragma unroll
      for (int i = 0; i < 2; ++i) {
        int ob = (w * 2 + i) * 1024;
        int o = ob + l * 16;
        int r = o >> 6;
        int c = ((o >> 4) & 3) ^ ((r + (r >> 2)) & 3);
        const u16* g = gp + (size_t)(n0 + r) * Kd + k0 + c * 8;
        __builtin_amdgcn_global_load_lds(
            (const __attribute__((address_space(1))) unsigned int*)(const void*)g,
            (__attribute__((address_space(3))) unsigned int*)(void*)(lb + (ob >> 1)), 16, 0, 0);
      }
    }
#pragma unroll
    for (int p = 0; p < 4; ++p) {
      int e = p * 256 + t;
      int r = e >> 3, kc = (e & 7) * 4;
      float4 a = *(const float4*)(Af + (size_t)(m0 + r) * Kd + k0 + kc);
      u16 h0, h1, h2, h3, q0, q1, q2, q3;
      splitf16(a.x, h0, q0); splitf16(a.y, h1, q1); splitf16(a.z, h2, q2); splitf16(a.w, h3, q3);
      int idx = r * 32 + ((((kc >> 3) ^ ((r + (r >> 2)) & 3))) << 3) + (kc & 7);
      *(uint2*)&As[0][idx] = make_uint2((unsigned)h0 | ((unsigned)h1 << 16), (unsigned)h2 | ((unsigned)h3 << 16));
      *(uint2*)&As[1][idx] = make_uint2((unsigned)q0 | ((unsigned)q1 << 16), (unsigned)q2 | ((unsigned)q3 << 16));
    }
    __syncthreads();
    half8 ah[4], al[4], bh4[4], bl4[4];
#pragma unroll
    for (int mi = 0; mi < 4; ++mi) {
      int r = wr * 64 + mi * 16 + lr;
      int idx = r * 32 + ((lg ^ ((r + (r >> 2)) & 3)) << 3);
      ah[mi] = *(const half8*)&As[0][idx];
      al[mi] = *(const half8*)&As[1][idx];
    }
#pragma unroll
    for (int ni = 0; ni < 4; ++ni) {
      int r = wc * 64 + ni * 16 + lr;
      int idx = r * 32 + ((lg ^ ((r + (r >> 2)) & 3)) << 3);
      bh4[ni] = *(const half8*)&Bs[0][idx];
      bl4[ni] = *(const half8*)&Bs[1][idx];
    }
#pragma unroll
    for (int mi = 0; mi < 4; ++mi)
#pragma unroll
      for (int ni = 0; ni < 4; ++ni) {
        acc[mi][ni] = __builtin_amdgcn_mfma_f32_16x16x32_f16(ah[mi], bh4[ni], acc[mi][ni], 0, 0, 0);
        acc[mi][ni] = __builtin_amdgcn_mfma_f32_16x16x32_f16(ah[mi], bl4[ni], acc[mi][ni], 0, 0, 0);
        acc[mi][ni] = __builtin_amdgcn_mfma_f32_16x16x32_f16(al[mi], bh4[ni], acc[mi][ni], 0, 0, 0);
      }
    __syncthreads();
  }

  float bv[4];
#pragma unroll
  for (int ni = 0; ni < 4; ++ni) bv[ni] = bias[n0 + wc * 64 + ni * 16 + lr];
#pragma unroll
  for (int mi = 0; mi < 4; ++mi)
#pragma unroll
    for (int j = 0; j < 4; ++j) {
      int m = m0 + wr * 64 + mi * 16 + lg * 4 + j;
#pragma unroll
      for (int ni = 0; ni < 4; ++ni) {
        int n = n0 + wc * 64 + ni * 16 + lr;
        float o = acc[mi][ni][j] + bv[ni];
        if (EPI == 1) o = fmaxf(o, 0.f);
        C[(size_t)m * N + n] = o;
      }
    }
}

// ===================== MFMA flash attention (round-10 proven: Q in regs, setprio) =====================
__global__ __launch_bounds__(512) void attn_mfma(const float* __restrict__ Q,
    const float* __restrict__ Kx, const float* __restrict__ V, float* __restrict__ O) {
  __shared__ __align__(16) u16 Ks[2][4608];   // [64 key][72]
  __shared__ __align__(16) u16 Ps[2][9216];   // [128 q][72]
  __shared__ __align__(16) u16 Vt[2][4608];   // [64 d][72]
  const int t = threadIdx.x;
  const int w = t >> 6, l = t & 63;
  const int lr = l & 15, lg = l >> 4;
  const int bh = blockIdx.y;
  const int q0 = blockIdx.x * 128;
  const float* Qb = Q + ((size_t)bh * 512 + q0) * 64;
  const float* Kb = Kx + (size_t)bh * 512 * 64;
  const float* Vb = V + (size_t)bh * 512 * 64;

  half8 qh[2], qlo[2];
#pragma unroll
  for (int ks = 0; ks < 2; ++ks) {
    const float* p = Qb + (size_t)(w * 16 + lr) * 64 + ks * 32 + lg * 8;
    float4 f0 = *(const float4*)p;
    float4 f1 = *(const float4*)(p + 4);
    float v8[8] = {f0.x, f0.y, f0.z, f0.w, f1.x, f1.y, f1.z, f1.w};
#pragma unroll
    for (int j = 0; j < 8; ++j) {
      _Float16 hh = (_Float16)v8[j];
      float r = v8[j] - (float)hh;
      qh[ks][j] = hh;
      qlo[ks][j] = (_Float16)r;
    }
  }

  float mrun[4] = {-1e30f, -1e30f, -1e30f, -1e30f};
  float lrun[4] = {0.f, 0.f, 0.f, 0.f};
  f32x4 o[4];
  const f32x4 zf = {0.f, 0.f, 0.f, 0.f};
#pragma unroll
  for (int dn = 0; dn < 4; ++dn) o[dn] = zf;

#pragma unroll 1
  for (int kc = 0; kc < 8; ++kc) {
    __syncthreads();
#pragma unroll
    for (int i = 0; i < 2; ++i) {
      int e = i * 512 + t;
      int row = e >> 4, c4 = (e & 15) * 4;
      float4 kv4 = *(const float4*)(Kb + (size_t)(kc * 64 + row) * 64 + c4);
      u16 h0, h1, h2, h3, l0, l1, l2, l3;
      splitf16(kv4.x, h0, l0); splitf16(kv4.y, h1, l1); splitf16(kv4.z, h2, l2); splitf16(kv4.w, h3, l3);
      *(uint2*)&Ks[0][row * 72 + c4] = make_uint2((unsigned)h0 | ((unsigned)h1 << 16), (unsigned)h2 | ((unsigned)h3 << 16));
      *(uint2*)&Ks[1][row * 72 + c4] = make_uint2((unsigned)l0 | ((unsigned)l1 << 16), (unsigned)l2 | ((unsigned)l3 << 16));
      float4 vv4 = *(const float4*)(Vb + (size_t)(kc * 64 + row) * 64 + c4);
      u16 vh[4], vl[4];
      splitf16(vv4.x, vh[0], vl[0]); splitf16(vv4.y, vh[1], vl[1]);
      splitf16(vv4.z, vh[2], vl[2]); splitf16(vv4.w, vh[3], vl[3]);
#pragma unroll
      for (int ii = 0; ii < 4; ++ii) {
        Vt[0][(c4 + ii) * 72 + row] = vh[ii];
        Vt[1][(c4 + ii) * 72 + row] = vl[ii];
      }
    }
    __syncthreads();
    f32x4 sa[4];
#pragma unroll
    for (int ni = 0; ni < 4; ++ni) sa[ni] = zf;
    __builtin_amdgcn_s_setprio(1);
#pragma unroll
    for (int ks = 0; ks < 2; ++ks) {
#pragma unroll
      for (int ni = 0; ni < 4; ++ni) {
        half8 kh = *(const half8*)&Ks[0][(ni * 16 + lr) * 72 + ks * 32 + lg * 8];
        half8 klo = *(const half8*)&Ks[1][(ni * 16 + lr) * 72 + ks * 32 + lg * 8];
        sa[ni] = __builtin_amdgcn_mfma_f32_16x16x32_f16(qh[ks], kh, sa[ni], 0, 0, 0);
        sa[ni] = __builtin_amdgcn_mfma_f32_16x16x32_f16(qh[ks], klo, sa[ni], 0, 0, 0);
        sa[ni] = __builtin_amdgcn_mfma_f32_16x16x32_f16(qlo[ks], kh, sa[ni], 0, 0, 0);
      }
    }
    __builtin_amdgcn_s_setprio(0);
#pragma unroll
    for (int j = 0; j < 4; ++j) {
      float sv[4];
#pragma unroll
      for (int ni = 0; ni < 4; ++ni) sv[ni] = sa[ni][j] * 8.f;
      float mx = fmaxf(fmaxf(sv[0], sv[1]), fmaxf(sv[2], sv[3]));
#pragma unroll
      for (int off = 8; off; off >>= 1) mx = fmaxf(mx, __shfl_xor(mx, off, 16));
      float mnew = fmaxf(mrun[j], mx);
      float fac = expf(mrun[j] - mnew);
      float ps = 0.f;
#pragma unroll
      for (int ni = 0; ni < 4; ++ni) {
        float p = expf(sv[ni] - mnew);
        ps += p;
        u16 ph_, pl_;
        splitf16(p, ph_, pl_);
        Ps[0][(w * 16 + lg * 4 + j) * 72 + ni * 16 + lr] = ph_;
        Ps[1][(w * 16 + lg * 4 + j) * 72 + ni * 16 + lr] = pl_;
      }
#pragma unroll
      for (int off = 8; off; off >>= 1) ps += __shfl_xor(ps, off, 16);
      lrun[j] = lrun[j] * fac + ps;
      mrun[j] = mnew;
#pragma unroll
      for (int dn = 0; dn < 4; ++dn) o[dn][j] *= fac;
    }
    __builtin_amdgcn_s_setprio(1);
#pragma unroll
    for (int ks = 0; ks < 2; ++ks) {
      half8 ph8 = *(const half8*)&Ps[0][(w * 16 + lr) * 72 + ks * 32 + lg * 8];
      half8 pl8 = *(const half8*)&Ps[1][(w * 16 + lr) * 72 + ks * 32 + lg * 8];
#pragma unroll
      for (int dn = 0; dn < 4; ++dn) {
        half8 vh8 = *(const half8*)&Vt[0][(dn * 16 + lr) * 72 + ks * 32 + lg * 8];
        half8 vl8 = *(const half8*)&Vt[1][(dn * 16 + lr) * 72 + ks * 32 + lg * 8];
        o[dn] = __builtin_amdgcn_mfma_f32_16x16x32_f16(ph8, vh8, o[dn], 0, 0, 0);
        o[dn] = __builtin_amdgcn_mfma_f32_16x16x32_f16(ph8, vl8, o[dn], 0, 0, 0);
        o[dn] = __builtin_amdgcn_mfma_f32_16x16x32_f16(pl8, vh8, o[dn], 0, 0, 0);
      }
    }
    __builtin_amdgcn_s_setprio(0);
  }
  float inv[4];
#pragma unroll
  for (int j = 0; j < 4; ++j) inv[j] = 1.f / lrun[j];
  float* Ob = O + ((size_t)bh * 512 + q0) * 64;
#pragma unroll
  for (int dn = 0; dn < 4; ++dn)
#pragma unroll
    for (int j = 0; j < 4; ++j)
      Ob[(size_t)(w * 16 + lg * 4 + j) * 64 + dn * 16 + lr] = o[dn][j] * inv[j];
}

// ===================== VQ 256x256, 16 waves, L2-locality block order (round-11 proven) =====================
__global__ __launch_bounds__(1024) void vq256(
    const u16* __restrict__ Ahi, const u16* __restrict__ Alo,
    const u16* __restrict__ Bhi, const u16* __restrict__ Blo,
    const float* __restrict__ zn, const float* __restrict__ cn,
    unsigned long long* __restrict__ best) {
  __shared__ __align__(16) u16 As[2][2][8192];   // [buf][plane][256*32]
  __shared__ __align__(16) u16 Bs[2][2][8192];
  const int t = threadIdx.x;
  const int w = t >> 6, l = t & 63;
  const int lr = l & 15, lg = l >> 4;
  const int wr = w >> 2, wc = w & 3;
  const int f = blockIdx.x;
  const int xcd = f & 7, pos = f >> 3;
  const int ml = pos & 15;          // 16 m-panels, fastest
  const int nl = pos >> 4;          // 8 n-panels per XCD, slowest
  const int n0 = (xcd * 8 + nl) * 256;
  const int m0 = ml * 256;

  f32x4 acc[4][4];
  const f32x4 zf = {0.f, 0.f, 0.f, 0.f};
#pragma unroll
  for (int mi = 0; mi < 4; ++mi)
#pragma unroll
    for (int ni = 0; ni < 4; ++ni) acc[mi][ni] = zf;

  const int s_ob = w * 1024;
  int s_r, s_c;
  {
    int o = s_ob + l * 16;
    s_r = o >> 6;
    s_c = ((o >> 4) & 3) ^ ((s_r + (s_r >> 2)) & 3);
  }

#define VQ_STAGE(buf, k0)                                                               \
  {                                                                                     \
    size_t ea = (size_t)(m0 + s_r) * 512 + (k0) + s_c * 8;                              \
    size_t eb = (size_t)(n0 + s_r) * 512 + (k0) + s_c * 8;                              \
    __builtin_amdgcn_global_load_lds(                                                   \
        (const __attribute__((address_space(1))) unsigned int*)(const void*)(Ahi + ea), \
        (__attribute__((address_space(3))) unsigned int*)(void*)(&As[buf][0][s_ob >> 1]), 16, 0, 0); \
    __builtin_amdgcn_global_load_lds(                                                   \
        (const __attribute__((address_space(1))) unsigned int*)(const void*)(Alo + ea), \
        (__attribute__((address_space(3))) unsigned int*)(void*)(&As[buf][1][s_ob >> 1]), 16, 0, 0); \
    __builtin_amdgcn_global_load_lds(                                                   \
        (const __attribute__((address_space(1))) unsigned int*)(const void*)(Bhi + eb), \
        (__attribute__((address_space(3))) unsigned int*)(void*)(&Bs[buf][0][s_ob >> 1]), 16, 0, 0); \
    __builtin_amdgcn_global_load_lds(                                                   \
        (const __attribute__((address_space(1))) unsigned int*)(const void*)(Blo + eb), \
        (__attribute__((address_space(3))) unsigned int*)(void*)(&Bs[buf][1][s_ob >> 1]), 16, 0, 0); \
  }

#define VQ_COMPUTE(buf)                                                                 \
  {                                                                                     \
    half8 bh[4], bl[4];                                                                 \
    _Pragma("unroll")                                                                   \
    for (int ni = 0; ni < 4; ++ni) {                                                    \
      int r = wc * 64 + ni * 16 + lr;                                                   \
      int idx = r * 32 + ((lg ^ ((r + (r >> 2)) & 3)) << 3);                            \
      bh[ni] = *(const half8*)&Bs[buf][0][idx];                                         \
      bl[ni] = *(const half8*)&Bs[buf][1][idx];                                         \
    }                                                                                   \
    _Pragma("unroll")                                                                   \
    for (int mi = 0; mi < 4; ++mi) {                                                    \
      int r = wr * 64 + mi * 16 + lr;                                                   \
      int idx = r * 32 + ((lg ^ ((r + (r >> 2)) & 3)) << 3);                            \
      half8 ah = *(const half8*)&As[buf][0][idx];                                       \
      half8 al = *(const half8*)&As[buf][1][idx];                                       \
      _Pragma("unroll")                                                                 \
      for (int ni = 0; ni < 4; ++ni) {                                                  \
        acc[mi][ni] = __builtin_amdgcn_mfma_f32_16x16x32_f16(ah, bh[ni], acc[mi][ni], 0, 0, 0); \
        acc[mi][ni] = __builtin_amdgcn_mfma_f32_16x16x32_f16(ah, bl[ni], acc[mi][ni], 0, 0, 0); \
        acc[mi][ni] = __builtin_amdgcn_mfma_f32_16x16x32_f16(al, bh[ni], acc[mi][ni], 0, 0, 0); \
      }                                                                                 \
    }                                                                                   \
  }

  VQ_STAGE(0, 0);
  asm volatile("s_waitcnt vmcnt(0)" ::: "memory");
  __builtin_amdgcn_s_barrier();
  int cur = 0;
#pragma unroll 1
  for (int ks = 0; ks < 16; ++ks) {
    if (ks < 15) VQ_STAGE(cur ^ 1, (ks + 1) * 32);
    VQ_COMPUTE(cur);
    asm volatile("s_waitcnt vmcnt(0)" ::: "memory");
    __builtin_amdgcn_s_barrier();
    cur ^= 1;
  }

  float cnv[4];
#pragma unroll
  for (int ni = 0; ni < 4; ++ni) cnv[ni] = cn[n0 + wc * 64 + ni * 16 + lr];
#pragma unroll
  for (int mi = 0; mi < 4; ++mi)
#pragma unroll
    for (int j = 0; j < 4; ++j) {
      int m = m0 + wr * 64 + mi * 16 + lg * 4 + j;
      float zr = zn[m];
      float db = 3.4e38f; int jb = 0;
#pragma unroll
      for (int ni = 0; ni < 4; ++ni) {
        float dd = zr + cnv[ni] - 2.f * acc[mi][ni][j];
        int nn = n0 + wc * 64 + ni * 16 + lr;
        if (dd < db) { db = dd; jb = nn; }
      }
      unsigned long long key = ((unsigned long long)fkey(db) << 32) | (unsigned int)jb;
#pragma unroll
      for (int off = 8; off; off >>= 1) {
        unsigned long long o = __shfl_xor(key, off, 16);
        if (o < key) key = o;
      }
      if (lr == 0) atomicMin(best + m, key);
    }
#undef VQ_STAGE
#undef VQ_COMPUTE
}

// ===================== per-layer weight transpose+split =====================
__global__ __launch_bounds__(256) void wcvt_layer(const float* __restrict__ Wq,
    const float* __restrict__ Wk, const float* __restrict__ Wv, const float* __restrict__ Wo,
    const float* __restrict__ W1, const float* __restrict__ W2, u16* __restrict__ wt) {
  __shared__ float Ls[64][68];
  const int T = blockIdx.x, t = threadIdx.x;
  const float* src; u16 *dh, *dl; int K, N, kt, nt;
  if (T < 256) {
    int mat = T >> 6, tt = T & 63;
    src = (mat == 0) ? Wq : (mat == 1) ? Wk : (mat == 2) ? Wv : Wo;
    dh = wt + (size_t)mat * 524288; dl = dh + 262144;
    K = 512; N = 512; kt = tt >> 3; nt = tt & 7;
  } else if (T < 512) {
    int tt = T - 256; src = W1; dh = wt + 2097152; dl = dh + 1048576;
    K = 512; N = 2048; kt = tt >> 5; nt = tt & 31;
  } else {
    int tt = T - 512; src = W2; dh = wt + 4194304; dl = dh + 1048576;
    K = 2048; N = 512; kt = tt >> 3; nt = tt & 7;
  }
  const int k0 = kt * 64, n0 = nt * 64;
#pragma unroll
  for (int p = 0; p < 4; ++p) {
    int e = p * 256 + t;
    int kr = e >> 4, nc = (e & 15) * 4;
    *(float4*)&Ls[kr][nc] = *(const float4*)(src + (size_t)(k0 + kr) * N + n0 + nc);
  }
  __syncthreads();
  {
    int n = t >> 2, kc = (t & 3) * 16;
    unsigned hw[8], lw[8];
#pragma unroll
    for (int i = 0; i < 8; ++i) {
      u16 ha, la, hb, lb;
      splitf16(Ls[kc + 2 * i][n], ha, la);
      splitf16(Ls[kc + 2 * i + 1][n], hb, lb);
      hw[i] = (unsigned)ha | ((unsigned)hb << 16);
      lw[i] = (unsigned)la | ((unsigned)lb << 16);
    }
    size_t o = (size_t)(n0 + n) * K + k0 + kc;
    *(uint4*)&dh[o] = make_uint4(hw[0], hw[1], hw[2], hw[3]);
    *(uint4*)&dh[o + 8] = make_uint4(hw[4], hw[5], hw[6], hw[7]);
    *(uint4*)&dl[o] = make_uint4(lw[0], lw[1], lw[2], lw[3]);
    *(uint4*)&dl[o + 8] = make_uint4(lw[4], lw[5], lw[6], lw[7]);
  }
}

// ===================== row split to fp16 planes + row sumsq =====================
__global__ __launch_bounds__(128) void zcvt_kernel(const float* __restrict__ src,
    u16* __restrict__ hi, u16* __restrict__ lo, float* __restrict__ nrm) {
  __shared__ float red[2];
  const int row = blockIdx.x, t = threadIdx.x;
  const float4 a = *(const float4*)(src + (size_t)row * 512 + t * 4);
  u16 h0, h1, h2, h3, q0, q1, q2, q3;
  splitf16(a.x, h0, q0); splitf16(a.y, h1, q1); splitf16(a.z, h2, q2); splitf16(a.w, h3, q3);
  *(uint2*)&hi[(size_t)row * 512 + t * 4] = make_uint2((unsigned)h0 | ((unsigned)h1 << 16), (unsigned)h2 | ((unsigned)h3 << 16));
  *(uint2*)&lo[(size_t)row * 512 + t * 4] = make_uint2((unsigned)q0 | ((unsigned)q1 << 16), (unsigned)q2 | ((unsigned)q3 << 16));
  float s = a.x * a.x + a.y * a.y + a.z * a.z + a.w * a.w;
#pragma unroll
  for (int off = 32; off; off >>= 1) s += __shfl_xor(s, off, 64);
  if ((t & 63) == 0) red[t >> 6] = s;
  __syncthreads();
  if (t == 0) nrm[row] = red[0] + red[1];
}

// ======================= residual add + LayerNorm =======================
__global__ __launch_bounds__(128) void ln_kernel(const float* __restrict__ A,
    const float* __restrict__ Dl, const float* __restrict__ g,
    const float* __restrict__ bb, float* __restrict__ out) {
  __shared__ float red[2];
  const int row = blockIdx.x, t = threadIdx.x;
  const float4 a = *(const float4*)(A + (size_t)row * 512 + t * 4);
  const float4 d = *(const float4*)(Dl + (size_t)row * 512 + t * 4);
  float v0 = a.x + d.x, v1 = a.y + d.y, v2 = a.z + d.z, v3 = a.w + d.w;
  float s = v0 + v1 + v2 + v3;
#pragma unroll
  for (int off = 32; off; off >>= 1) s += __shfl_xor(s, off, 64);
  if ((t & 63) == 0) red[t >> 6] = s;
  __syncthreads();
  const float mu = (red[0] + red[1]) * (1.f / 512.f);
  const float w0 = v0 - mu, w1 = v1 - mu, w2 = v2 - mu, w3 = v3 - mu;
  float q = w0 * w0 + w1 * w1 + w2 * w2 + w3 * w3;
  __syncthreads();
#pragma unroll
  for (int off = 32; off; off >>= 1) q += __shfl_xor(q, off, 64);
  if ((t & 63) == 0) red[t >> 6] = q;
  __syncthreads();
  const float rs = rsqrtf((red[0] + red[1]) * (1.f / 512.f) + LN_EPS);
  const float4 gv = *(const float4*)(g + t * 4);
  const float4 bv = *(const float4*)(bb + t * 4);
  *(float4*)(out + (size_t)row * 512 + t * 4) =
      make_float4(w0 * rs * gv.x + bv.x, w1 * rs * gv.y + bv.y, w2 * rs * gv.z + bv.z, w3 * rs * gv.w + bv.w);
}

// ======================= gather zq, idx(as float), per-row loss, histogram =======================
__global__ __launch_bounds__(128) void gather_kernel(const unsigned long long* __restrict__ best,
    const float* __restrict__ Cb, const float* __restrict__ Ze, float* __restrict__ zq,
    float* __restrict__ oidx, float* __restrict__ rloss, int* __restrict__ hist) {
  __shared__ float red[2];
  const int row = blockIdx.x, t = threadIdx.x;
  const int idx = (int)(best[row] & 0xFFFFFFFFULL);
  const float4 c = *(const float4*)(Cb + (size_t)idx * 512 + t * 4);
  const float4 z = *(const float4*)(Ze + (size_t)row * 512 + t * 4);
  *(float4*)(zq + (size_t)row * 512 + t * 4) = c;
  const float d0 = c.x - z.x, d1 = c.y - z.y, d2 = c.z - z.z, d3 = c.w - z.w;
  float s = d0 * d0 + d1 * d1 + d2 * d2 + d3 * d3;
#pragma unroll
  for (int off = 32; off; off >>= 1) s += __shfl_xor(s, off, 64);
  if ((t & 63) == 0) red[t >> 6] = s;
  __syncthreads();
  if (t == 0) {
    rloss[row] = red[0] + red[1];
    oidx[row] = (float)idx;
    atomicAdd(hist + idx, 1);
  }
}

// ======================= finalize loss + perplexity =======================
__global__ __launch_bounds__(256) void fin_kernel(const float* __restrict__ rloss,
    const int* __restrict__ hist, float* __restrict__ oloss, float* __restrict__ oppl) {
  __shared__ float red[4];
  const int t = threadIdx.x;
  float s = 0.f;
  for (int i = t; i < 4096; i += 256) s += rloss[i];
#pragma unroll
  for (int off = 32; off; off >>= 1) s += __shfl_xor(s, off, 64);
  if ((t & 63) == 0) red[t >> 6] = s;
  __syncthreads();
  if (t == 0) oloss[0] = 0.25f * (red[0] + red[1] + red[2] + red[3]) * (1.f / 2097152.f);
  float e = 0.f;
  for (int i = t; i < KCB; i += 256) {
    float p = (float)hist[i] * (1.f / 4096.f);
    e += p * logf(p + 1e-10f);
  }
#pragma unroll
  for (int off = 32; off; off >>= 1) e += __shfl_xor(e, off, 64);
  __syncthreads();
  if ((t & 63) == 0) red[t >> 6] = e;
  __syncthreads();
  if (t == 0) oppl[0] = expf(-(red[0] + red[1] + red[2] + red[3]));
}

extern "C" void kernel_launch(void* const* d_in, const int* in_sizes, int n_in,
                              void* d_out, int out_size, void* d_ws, size_t ws_size,
                              hipStream_t stream) {
  const float* vec  = (const float*)d_in[0];
  const float* Wq   = (const float*)d_in[1];
  const float* bq   = (const float*)d_in[2];
  const float* Wk   = (const float*)d_in[3];
  const float* bk   = (const float*)d_in[4];
  const float* Wv   = (const float*)d_in[5];
  const float* bv   = (const float*)d_in[6];
  const float* Wo   = (const float*)d_in[7];
  const float* bo   = (const float*)d_in[8];
  const float* l1g  = (const float*)d_in[9];
  const float* l1b  = (const float*)d_in[10];
  const float* W1   = (const float*)d_in[11];
  const float* b1   = (const float*)d_in[12];
  const float* W2   = (const float*)d_in[13];
  const float* b2   = (const float*)d_in[14];
  const float* l2g  = (const float*)d_in[15];
  const float* l2b  = (const float*)d_in[16];
  const float* cb   = (const float*)d_in[17];

  char* wsb = (char*)d_ws;
  float* x   = (float*)(wsb + B_X);
  float* q   = (float*)(wsb + B_Q);
  float* k   = (float*)(wsb + B_K);
  float* v   = (float*)(wsb + B_V);
  float* ctx = (float*)(wsb + B_CT);
  float* tmp = (float*)(wsb + B_TMP);
  float* h   = (float*)(wsb + B_H);
  u16* cbh = (u16*)(wsb + B_CBH);
  u16* cbl = (u16*)(wsb + B_CBL);
  u16* zeh = (u16*)(wsb + B_ZEH);
  u16* zel = (u16*)(wsb + B_ZEL);
  float* zn = (float*)(wsb + B_ZN);
  float* cn = (float*)(wsb + B_CN);
  float* rl = (float*)(wsb + B_RL);
  unsigned long long* best = (unsigned long long*)(wsb + B_BEST);
  int* hist = (int*)(wsb + B_HIST);
  u16* wt = (u16*)(wsb + B_WT);
  u16* wto_h = wt + 1572864;      u16* wto_l = wt + 1835008;
  u16* wt1_h = wt + 2097152;      u16* wt1_l = wt + 3145728;
  u16* wt2_h = wt + 4194304;      u16* wt2_l = wt + 5242880;

  float* zq   = (float*)d_out;
  float* oidx = (float*)d_out + 2097152;
  float* olos = (float*)d_out + 2097152 + 4096;
  float* oppl = olos + 1;

  const dim3 gQkv(4, 64, 3);   // 64x128 tiles x {Q,K,V}
  const dim3 gProj(4, 64);     // 64x128 tiles
  const dim3 gFfn1(16, 32);    // 128x128 tiles
  const dim3 gAttn(4, 64);     // 128 q-rows x 64 bh

  for (int l = 0; l < NLAY; ++l) {
    const float* xin = l ? (const float*)x : vec;
    const size_t wo = (size_t)l * DDIM * DDIM;
    wcvt_layer<<<768, 256, 0, stream>>>(Wq + wo, Wk + wo, Wv + wo, Wo + wo,
        W1 + (size_t)l * DDIM * FFND, W2 + (size_t)l * FFND * DDIM, wt);
    qkv_enc<<<gQkv, 256, 0, stream>>>(xin, wt, bq + l * DDIM, bk + l * DDIM, bv + l * DDIM, q);
    attn_mfma<<<gAttn, 512, 0, stream>>>(q, k, v, ctx);
    gemm_enc_p<0><<<gProj, 256, 0, stream>>>(ctx, wto_h, wto_l, bo + l * DDIM, tmp, DDIM, DDIM);
    ln_kernel<<<MROWS, 128, 0, stream>>>(xin, tmp, l1g + l * DDIM, l1b + l * DDIM, x);
    gemm128<1><<<gFfn1, 256, 0, stream>>>(x, wt1_h, wt1_l, b1 + l * FFND, h, DDIM, FFND);
    gemm_enc_p<0><<<gProj, 256, 0, stream>>>(h, wt2_h, wt2_l, b2 + l * DDIM, tmp, FFND, DDIM);
    ln_kernel<<<MROWS, 128, 0, stream>>>(x, tmp, l2g + l * DDIM, l2b + l * DDIM, x);
  }

  zcvt_kernel<<<MROWS, 128, 0, stream>>>(x, zeh, zel, zn);
  zcvt_kernel<<<KCB, 128, 0, stream>>>(cb, cbh, cbl, cn);
  hipMemsetAsync(best, 0xFF, 4096 * 8, stream);
  hipMemsetAsync(hist, 0, KCB * 4, stream);
  vq256<<<1024, 1024, 0, stream>>>(zeh, zel, cbh, cbl, zn, cn, best);
  gather_kernel<<<MROWS, 128, 0, stream>>>(best, cb, x, zq, oidx, rl, hist);
  fin_kernel<<<1, 256, 0, stream>>>(rl, hist, olos, oppl);
}

// Round 13
// 1032.597 us; speedup vs baseline: 1.0103x; 1.0103x over previous
//
#include <hip/hip_runtime.h>

#define MROWS 4096
#define DDIM  512
#define FFND  2048
#define NLAY  4
#define KCB   16384
#define LN_EPS 1e-5f

typedef unsigned short u16;
typedef _Float16 half8 __attribute__((ext_vector_type(8)));
typedef float f32x4 __attribute__((ext_vector_type(4)));

// ---- workspace layout (byte offsets) ----
#define B_X    0ULL
#define B_Q    8388608ULL
#define B_K    16777216ULL
#define B_V    25165824ULL
#define B_CT   33554432ULL
#define B_TMP  41943040ULL
#define B_H    8388608ULL
#define B_CBH  8388608ULL
#define B_CBL  25165824ULL
#define B_ZEH  41943040ULL
#define B_ZEL  46137344ULL
#define B_ZN   50331648ULL
#define B_CN   50348032ULL
#define B_RL   50413568ULL
#define B_BEST 50429952ULL
#define B_HIST 50462720ULL
#define B_WT   50528256ULL

// fp16 2-way split: x = h + l + eps, |eps| <= 2^-22|x|.
__device__ __forceinline__ void splitf16(float x, u16& h, u16& l) {
  _Float16 hh = (_Float16)x;          // RNE
  float r = x - (float)hh;            // exact
  _Float16 ll = (_Float16)r;          // RNE
  h = *(u16*)&hh; l = *(u16*)&ll;
}

__device__ __forceinline__ unsigned int fkey(float f) {
  unsigned int u = __float_as_uint(f);
  return (u & 0x80000000u) ? ~u : (u | 0x80000000u);
}

// ===================== 64x128 split-fp16 MFMA GEMM body (round-6/8 proven; qkv) =====================
template<int EPI>
__device__ __forceinline__ void gemm64_body(const float* __restrict__ Af,
    const u16* __restrict__ Bhi, const u16* __restrict__ Blo,
    const float* __restrict__ bias, float* __restrict__ C, int Kd, int N) {
  __shared__ __align__(16) u16 As[2][2048];   // 64 rows x 32 k
  __shared__ __align__(16) u16 Bs[2][4096];   // 128 rows x 32 k
  const int t = threadIdx.x;
  const int w = t >> 6, l = t & 63;
  const int lr = l & 15, lg = l >> 4;
  const int m0 = blockIdx.y * 64, n0 = blockIdx.x * 128;

  f32x4 acc[4][2];
  const f32x4 zf = {0.f, 0.f, 0.f, 0.f};
#pragma unroll
  for (int mi = 0; mi < 4; ++mi)
#pragma unroll
    for (int ni = 0; ni < 2; ++ni) acc[mi][ni] = zf;

  for (int k0 = 0; k0 < Kd; k0 += 32) {
#pragma unroll
    for (int pl = 0; pl < 2; ++pl) {
      const u16* gp = pl ? Blo : Bhi;
      u16* lb = &Bs[pl][0];
#pragma unroll
      for (int i = 0; i < 2; ++i) {
        int ob = w * 2048 + i * 1024;
        int o = ob + l * 16;
        int r = o >> 6;
        int pc = (o >> 4) & 3;
        int c = pc ^ ((r + (r >> 2)) & 3);
        const u16* g = gp + (size_t)(n0 + r) * Kd + k0 + c * 8;
        __builtin_amdgcn_global_load_lds(
            (const __attribute__((address_space(1))) unsigned int*)(const void*)g,
            (__attribute__((address_space(3))) unsigned int*)(void*)(lb + (ob >> 1)), 16, 0, 0);
      }
    }
#pragma unroll
    for (int p = 0; p < 2; ++p) {
      int e = p * 256 + t;
      int r = e >> 3, kc = (e & 7) * 4;
      float4 a = *(const float4*)(Af + (size_t)(m0 + r) * Kd + k0 + kc);
      u16 h0, h1, h2, h3, q0, q1, q2, q3;
      splitf16(a.x, h0, q0); splitf16(a.y, h1, q1); splitf16(a.z, h2, q2); splitf16(a.w, h3, q3);
      int idx = r * 32 + ((((kc >> 3) ^ ((r + (r >> 2)) & 3))) << 3) + (kc & 7);
      *(uint2*)&As[0][idx] = make_uint2((unsigned)h0 | ((unsigned)h1 << 16), (unsigned)h2 | ((unsigned)h3 << 16));
      *(uint2*)&As[1][idx] = make_uint2((unsigned)q0 | ((unsigned)q1 << 16), (unsigned)q2 | ((unsigned)q3 << 16));
    }
    __syncthreads();
    half8 ah[4], al[4], bh2[2], bl2[2];
#pragma unroll
    for (int mi = 0; mi < 4; ++mi) {
      int r = mi * 16 + lr;
      int idx = r * 32 + ((lg ^ ((r + (r >> 2)) & 3)) << 3);
      ah[mi] = *(const half8*)&As[0][idx];
      al[mi] = *(const half8*)&As[1][idx];
    }
#pragma unroll
    for (int ni = 0; ni < 2; ++ni) {
      int r = w * 32 + ni * 16 + lr;
      int idx = r * 32 + ((lg ^ ((r + (r >> 2)) & 3)) << 3);
      bh2[ni] = *(const half8*)&Bs[0][idx];
      bl2[ni] = *(const half8*)&Bs[1][idx];
    }
#pragma unroll
    for (int mi = 0; mi < 4; ++mi)
#pragma unroll
      for (int ni = 0; ni < 2; ++ni) {
        acc[mi][ni] = __builtin_amdgcn_mfma_f32_16x16x32_f16(ah[mi], bh2[ni], acc[mi][ni], 0, 0, 0);
        acc[mi][ni] = __builtin_amdgcn_mfma_f32_16x16x32_f16(ah[mi], bl2[ni], acc[mi][ni], 0, 0, 0);
        acc[mi][ni] = __builtin_amdgcn_mfma_f32_16x16x32_f16(al[mi], bh2[ni], acc[mi][ni], 0, 0, 0);
      }
    __syncthreads();
  }

  float bv[2];
#pragma unroll
  for (int ni = 0; ni < 2; ++ni) bv[ni] = bias[n0 + w * 32 + ni * 16 + lr];
#pragma unroll
  for (int mi = 0; mi < 4; ++mi)
#pragma unroll
    for (int j = 0; j < 4; ++j) {
      int m = m0 + mi * 16 + lg * 4 + j;
#pragma unroll
      for (int ni = 0; ni < 2; ++ni) {
        int n = n0 + w * 32 + ni * 16 + lr;
        float o = acc[mi][ni][j] + bv[ni];
        if (EPI == 1) o = fmaxf(o, 0.f);
        C[(size_t)m * N + n] = o;
      }
    }
}

__global__ __launch_bounds__(256) void qkv_enc(const float* __restrict__ Af,
    const u16* __restrict__ wt, const float* __restrict__ bq, const float* __restrict__ bk,
    const float* __restrict__ bv_, float* __restrict__ Cq) {
  const int z = blockIdx.z;
  const u16* Bhi = wt + (size_t)z * 524288;
  const u16* Blo = Bhi + 262144;
  const float* bias = (z == 0) ? bq : (z == 1) ? bk : bv_;
  float* C = Cq + (size_t)z * 2097152;
  gemm64_body<0>(Af, Bhi, Blo, bias, C, 512, 512);
}

__global__ __launch_bounds__(256) void gemm_enc(const float* __restrict__ Af,
    const u16* __restrict__ Bhi, const u16* __restrict__ Blo,
    const float* __restrict__ bias, float* __restrict__ C, int Kd, int N) {
  gemm64_body<0>(Af, Bhi, Blo, bias, C, Kd, N);
}

// ===================== 128x128 split-fp16 MFMA GEMM (FFN1) =====================
template<int EPI>
__global__ __launch_bounds__(256) void gemm128(const float* __restrict__ Af,
    const u16* __restrict__ Bhi, const u16* __restrict__ Blo,
    const float* __restrict__ bias, float* __restrict__ C, int Kd, int N) {
  __shared__ __align__(16) u16 As[2][4096];
  __shared__ __align__(16) u16 Bs[2][4096];
  const int t = threadIdx.x;
  const int w = t >> 6, l = t & 63;
  const int lr = l & 15, lg = l >> 4;
  const int wr = w >> 1, wc = w & 1;
  const int m0 = blockIdx.y * 128, n0 = blockIdx.x * 128;

  f32x4 acc[4][4];
  const f32x4 zf = {0.f, 0.f, 0.f, 0.f};
#pragma unroll
  for (int mi = 0; mi < 4; ++mi)
#pragma unroll
    for (int ni = 0; ni < 4; ++ni) acc[mi][ni] = zf;

  for (int k0 = 0; k0 < Kd; k0 += 32) {
#pragma unroll
    for (int pl = 0; pl < 2; ++pl) {
      const u16* gp = pl ? Blo : Bhi;
      u16* lb = &Bs[pl][0];
#pragma unroll
      for (int i = 0; i < 2; ++i) {
        int ob = (w * 2 + i) * 1024;
        int o = ob + l * 16;
        int r = o >> 6;
        int c = ((o >> 4) & 3) ^ ((r + (r >> 2)) & 3);
        const u16* g = gp + (size_t)(n0 + r) * Kd + k0 + c * 8;
        __builtin_amdgcn_global_load_lds(
            (const __attribute__((address_space(1))) unsigned int*)(const void*)g,
            (__attribute__((address_space(3))) unsigned int*)(void*)(lb + (ob >> 1)), 16, 0, 0);
      }
    }
#pragma unroll
    for (int p = 0; p < 4; ++p) {
      int e = p * 256 + t;
      int r = e >> 3, kc = (e & 7) * 4;
      float4 a = *(const float4*)(Af + (size_t)(m0 + r) * Kd + k0 + kc);
      u16 h0, h1, h2, h3, q0, q1, q2, q3;
      splitf16(a.x, h0, q0); splitf16(a.y, h1, q1); splitf16(a.z, h2, q2); splitf16(a.w, h3, q3);
      int idx = r * 32 + ((((kc >> 3) ^ ((r + (r >> 2)) & 3))) << 3) + (kc & 7);
      *(uint2*)&As[0][idx] = make_uint2((unsigned)h0 | ((unsigned)h1 << 16), (unsigned)h2 | ((unsigned)h3 << 16));
      *(uint2*)&As[1][idx] = make_uint2((unsigned)q0 | ((unsigned)q1 << 16), (unsigned)q2 | ((unsigned)q3 << 16));
    }
    __syncthreads();
    half8 ah[4], al[4], bh4[4], bl4[4];
#pragma unroll
    for (int mi = 0; mi < 4; ++mi) {
      int r = wr * 64 + mi * 16 + lr;
      int idx = r * 32 + ((lg ^ ((r + (r >> 2)) & 3)) << 3);
      ah[mi] = *(const half8*)&As[0][idx];
      al[mi] = *(const half8*)&As[1][idx];
    }
#pragma unroll
    for (int ni = 0; ni < 4; ++ni) {
      int r = wc * 64 + ni * 16 + lr;
      int idx = r * 32 + ((lg ^ ((r + (r >> 2)) & 3)) << 3);
      bh4[ni] = *(const half8*)&Bs[0][idx];
      bl4[ni] = *(const half8*)&Bs[1][idx];
    }
#pragma unroll
    for (int mi = 0; mi < 4; ++mi)
#pragma unroll
      for (int ni = 0; ni < 4; ++ni) {
        acc[mi][ni] = __builtin_amdgcn_mfma_f32_16x16x32_f16(ah[mi], bh4[ni], acc[mi][ni], 0, 0, 0);
        acc[mi][ni] = __builtin_amdgcn_mfma_f32_16x16x32_f16(ah[mi], bl4[ni], acc[mi][ni], 0, 0, 0);
        acc[mi][ni] = __builtin_amdgcn_mfma_f32_16x16x32_f16(al[mi], bh4[ni], acc[mi][ni], 0, 0, 0);
      }
    __syncthreads();
  }

  float bv[4];
#pragma unroll
  for (int ni = 0; ni < 4; ++ni) bv[ni] = bias[n0 + wc * 64 + ni * 16 + lr];
#pragma unroll
  for (int mi = 0; mi < 4; ++mi)
#pragma unroll
    for (int j = 0; j < 4; ++j) {
      int m = m0 + wr * 64 + mi * 16 + lg * 4 + j;
#pragma unroll
      for (int ni = 0; ni < 4; ++ni) {
        int n = n0 + wc * 64 + ni * 16 + lr;
        float o = acc[mi][ni][j] + bv[ni];
        if (EPI == 1) o = fmaxf(o, 0.f);
        C[(size_t)m * N + n] = o;
      }
    }
}

// ===================== MFMA flash attention (T14 async-stage: K/V prefetched to regs) =====================
__global__ __launch_bounds__(512) void attn_mfma(const float* __restrict__ Q,
    const float* __restrict__ Kx, const float* __restrict__ V, float* __restrict__ O) {
  __shared__ __align__(16) u16 Ks[2][4608];   // [64 key][72]
  __shared__ __align__(16) u16 Ps[2][9216];   // [128 q][72]
  __shared__ __align__(16) u16 Vt[2][4608];   // [64 d][72]
  const int t = threadIdx.x;
  const int w = t >> 6, l = t & 63;
  const int lr = l & 15, lg = l >> 4;
  const int bh = blockIdx.y;
  const int q0 = blockIdx.x * 128;
  const float* Qb = Q + ((size_t)bh * 512 + q0) * 64;
  const float* Kb = Kx + (size_t)bh * 512 * 64;
  const float* Vb = V + (size_t)bh * 512 * 64;

  // per-thread staging coords: rows r_i = i*32 + (t>>4), col c4 = (t&15)*4
  const int srow = t >> 4, sc4 = (t & 15) * 4;

  half8 qh[2], qlo[2];
#pragma unroll
  for (int ks = 0; ks < 2; ++ks) {
    const float* p = Qb + (size_t)(w * 16 + lr) * 64 + ks * 32 + lg * 8;
    float4 f0 = *(const float4*)p;
    float4 f1 = *(const float4*)(p + 4);
    float v8[8] = {f0.x, f0.y, f0.z, f0.w, f1.x, f1.y, f1.z, f1.w};
#pragma unroll
    for (int j = 0; j < 8; ++j) {
      _Float16 hh = (_Float16)v8[j];
      float r = v8[j] - (float)hh;
      qh[ks][j] = hh;
      qlo[ks][j] = (_Float16)r;
    }
  }

  float mrun[4] = {-1e30f, -1e30f, -1e30f, -1e30f};
  float lrun[4] = {0.f, 0.f, 0.f, 0.f};
  f32x4 o[4];
  const f32x4 zf = {0.f, 0.f, 0.f, 0.f};
#pragma unroll
  for (int dn = 0; dn < 4; ++dn) o[dn] = zf;

  // prefetch chunk 0 K/V into registers
  float4 kreg[2], vreg[2];
#pragma unroll
  for (int i = 0; i < 2; ++i) {
    int row = i * 32 + srow;
    kreg[i] = *(const float4*)(Kb + (size_t)row * 64 + sc4);
    vreg[i] = *(const float4*)(Vb + (size_t)row * 64 + sc4);
  }

#pragma unroll 1
  for (int kc = 0; kc < 8; ++kc) {
    __syncthreads();   // prev chunk's QK/PV reads of Ks/Vt done
    // convert regs -> LDS (loads were issued a full compute-phase ago)
#pragma unroll
    for (int i = 0; i < 2; ++i) {
      int row = i * 32 + srow;
      u16 h0, h1, h2, h3, l0, l1, l2, l3;
      splitf16(kreg[i].x, h0, l0); splitf16(kreg[i].y, h1, l1);
      splitf16(kreg[i].z, h2, l2); splitf16(kreg[i].w, h3, l3);
      *(uint2*)&Ks[0][row * 72 + sc4] = make_uint2((unsigned)h0 | ((unsigned)h1 << 16), (unsigned)h2 | ((unsigned)h3 << 16));
      *(uint2*)&Ks[1][row * 72 + sc4] = make_uint2((unsigned)l0 | ((unsigned)l1 << 16), (unsigned)l2 | ((unsigned)l3 << 16));
      u16 vh[4], vl[4];
      splitf16(vreg[i].x, vh[0], vl[0]); splitf16(vreg[i].y, vh[1], vl[1]);
      splitf16(vreg[i].z, vh[2], vl[2]); splitf16(vreg[i].w, vh[3], vl[3]);
#pragma unroll
      for (int ii = 0; ii < 4; ++ii) {
        Vt[0][(sc4 + ii) * 72 + row] = vh[ii];
        Vt[1][(sc4 + ii) * 72 + row] = vl[ii];
      }
    }
    __syncthreads();
    // issue next chunk's loads (hidden under QK + softmax + PV)
    if (kc < 7) {
#pragma unroll
      for (int i = 0; i < 2; ++i) {
        int row = i * 32 + srow;
        kreg[i] = *(const float4*)(Kb + (size_t)((kc + 1) * 64 + row) * 64 + sc4);
        vreg[i] = *(const float4*)(Vb + (size_t)((kc + 1) * 64 + row) * 64 + sc4);
      }
    }
    // S = Q K^T (3-pass)
    f32x4 sa[4];
#pragma unroll
    for (int ni = 0; ni < 4; ++ni) sa[ni] = zf;
    __builtin_amdgcn_s_setprio(1);
#pragma unroll
    for (int ks = 0; ks < 2; ++ks) {
#pragma unroll
      for (int ni = 0; ni < 4; ++ni) {
        half8 kh = *(const half8*)&Ks[0][(ni * 16 + lr) * 72 + ks * 32 + lg * 8];
        half8 klo = *(const half8*)&Ks[1][(ni * 16 + lr) * 72 + ks * 32 + lg * 8];
        sa[ni] = __builtin_amdgcn_mfma_f32_16x16x32_f16(qh[ks], kh, sa[ni], 0, 0, 0);
        sa[ni] = __builtin_amdgcn_mfma_f32_16x16x32_f16(qh[ks], klo, sa[ni], 0, 0, 0);
        sa[ni] = __builtin_amdgcn_mfma_f32_16x16x32_f16(qlo[ks], kh, sa[ni], 0, 0, 0);
      }
    }
    __builtin_amdgcn_s_setprio(0);
    // online softmax
#pragma unroll
    for (int j = 0; j < 4; ++j) {
      float sv[4];
#pragma unroll
      for (int ni = 0; ni < 4; ++ni) sv[ni] = sa[ni][j] * 8.f;
      float mx = fmaxf(fmaxf(sv[0], sv[1]), fmaxf(sv[2], sv[3]));
#pragma unroll
      for (int off = 8; off; off >>= 1) mx = fmaxf(mx, __shfl_xor(mx, off, 16));
      float mnew = fmaxf(mrun[j], mx);
      float fac = expf(mrun[j] - mnew);
      float ps = 0.f;
#pragma unroll
      for (int ni = 0; ni < 4; ++ni) {
        float p = expf(sv[ni] - mnew);
        ps += p;
        u16 ph_, pl_;
        splitf16(p, ph_, pl_);
        Ps[0][(w * 16 + lg * 4 + j) * 72 + ni * 16 + lr] = ph_;
        Ps[1][(w * 16 + lg * 4 + j) * 72 + ni * 16 + lr] = pl_;
      }
#pragma unroll
      for (int off = 8; off; off >>= 1) ps += __shfl_xor(ps, off, 16);
      lrun[j] = lrun[j] * fac + ps;
      mrun[j] = mnew;
#pragma unroll
      for (int dn = 0; dn < 4; ++dn) o[dn][j] *= fac;
    }
    // O += P V (3-pass)
    __builtin_amdgcn_s_setprio(1);
#pragma unroll
    for (int ks = 0; ks < 2; ++ks) {
      half8 ph8 = *(const half8*)&Ps[0][(w * 16 + lr) * 72 + ks * 32 + lg * 8];
      half8 pl8 = *(const half8*)&Ps[1][(w * 16 + lr) * 72 + ks * 32 + lg * 8];
#pragma unroll
      for (int dn = 0; dn < 4; ++dn) {
        half8 vh8 = *(const half8*)&Vt[0][(dn * 16 + lr) * 72 + ks * 32 + lg * 8];
        half8 vl8 = *(const half8*)&Vt[1][(dn * 16 + lr) * 72 + ks * 32 + lg * 8];
        o[dn] = __builtin_amdgcn_mfma_f32_16x16x32_f16(ph8, vh8, o[dn], 0, 0, 0);
        o[dn] = __builtin_amdgcn_mfma_f32_16x16x32_f16(ph8, vl8, o[dn], 0, 0, 0);
        o[dn] = __builtin_amdgcn_mfma_f32_16x16x32_f16(pl8, vh8, o[dn], 0, 0, 0);
      }
    }
    __builtin_amdgcn_s_setprio(0);
  }
  float inv[4];
#pragma unroll
  for (int j = 0; j < 4; ++j) inv[j] = 1.f / lrun[j];
  float* Ob = O + ((size_t)bh * 512 + q0) * 64;
#pragma unroll
  for (int dn = 0; dn < 4; ++dn)
#pragma unroll
    for (int j = 0; j < 4; ++j)
      Ob[(size_t)(w * 16 + lg * 4 + j) * 64 + dn * 16 + lr] = o[dn][j] * inv[j];
}

// ===================== VQ 256x256, 16 waves, L2-locality block order (round-11 proven) =====================
__global__ __launch_bounds__(1024) void vq256(
    const u16* __restrict__ Ahi, const u16* __restrict__ Alo,
    const u16* __restrict__ Bhi, const u16* __restrict__ Blo,
    const float* __restrict__ zn, const float* __restrict__ cn,
    unsigned long long* __restrict__ best) {
  __shared__ __align__(16) u16 As[2][2][8192];   // [buf][plane][256*32]
  __shared__ __align__(16) u16 Bs[2][2][8192];
  const int t = threadIdx.x;
  const int w = t >> 6, l = t & 63;
  const int lr = l & 15, lg = l >> 4;
  const int wr = w >> 2, wc = w & 3;
  const int f = blockIdx.x;
  const int xcd = f & 7, pos = f >> 3;
  const int ml = pos & 15;          // 16 m-panels, fastest
  const int nl = pos >> 4;          // 8 n-panels per XCD, slowest
  const int n0 = (xcd * 8 + nl) * 256;
  const int m0 = ml * 256;

  f32x4 acc[4][4];
  const f32x4 zf = {0.f, 0.f, 0.f, 0.f};
#pragma unroll
  for (int mi = 0; mi < 4; ++mi)
#pragma unroll
    for (int ni = 0; ni < 4; ++ni) acc[mi][ni] = zf;

  const int s_ob = w * 1024;
  int s_r, s_c;
  {
    int o = s_ob + l * 16;
    s_r = o >> 6;
    s_c = ((o >> 4) & 3) ^ ((s_r + (s_r >> 2)) & 3);
  }

#define VQ_STAGE(buf, k0)                                                               \
  {                                                                                     \
    size_t ea = (size_t)(m0 + s_r) * 512 + (k0) + s_c * 8;                              \
    size_t eb = (size_t)(n0 + s_r) * 512 + (k0) + s_c * 8;                              \
    __builtin_amdgcn_global_load_lds(                                                   \
        (const __attribute__((address_space(1))) unsigned int*)(const void*)(Ahi + ea), \
        (__attribute__((address_space(3))) unsigned int*)(void*)(&As[buf][0][s_ob >> 1]), 16, 0, 0); \
    __builtin_amdgcn_global_load_lds(                                                   \
        (const __attribute__((address_space(1))) unsigned int*)(const void*)(Alo + ea), \
        (__attribute__((address_space(3))) unsigned int*)(void*)(&As[buf][1][s_ob >> 1]), 16, 0, 0); \
    __builtin_amdgcn_global_load_lds(                                                   \
        (const __attribute__((address_space(1))) unsigned int*)(const void*)(Bhi + eb), \
        (__attribute__((address_space(3))) unsigned int*)(void*)(&Bs[buf][0][s_ob >> 1]), 16, 0, 0); \
    __builtin_amdgcn_global_load_lds(                                                   \
        (const __attribute__((address_space(1))) unsigned int*)(const void*)(Blo + eb), \
        (__attribute__((address_space(3))) unsigned int*)(void*)(&Bs[buf][1][s_ob >> 1]), 16, 0, 0); \
  }

#define VQ_COMPUTE(buf)                                                                 \
  {                                                                                     \
    half8 bh[4], bl[4];                                                                 \
    _Pragma("unroll")                                                                   \
    for (int ni = 0; ni < 4; ++ni) {                                                    \
      int r = wc * 64 + ni * 16 + lr;                                                   \
      int idx = r * 32 + ((lg ^ ((r + (r >> 2)) & 3)) << 3);                            \
      bh[ni] = *(const half8*)&Bs[buf][0][idx];                                         \
      bl[ni] = *(const half8*)&Bs[buf][1][idx];                                         \
    }                                                                                   \
    _Pragma("unroll")                                                                   \
    for (int mi = 0; mi < 4; ++mi) {                                                    \
      int r = wr * 64 + mi * 16 + lr;                                                   \
      int idx = r * 32 + ((lg ^ ((r + (r >> 2)) & 3)) << 3);                            \
      half8 ah = *(const half8*)&As[buf][0][idx];                                       \
      half8 al = *(const half8*)&As[buf][1][idx];                                       \
      _Pragma("unroll")                                                                 \
      for (int ni = 0; ni < 4; ++ni) {                                                  \
        acc[mi][ni] = __builtin_amdgcn_mfma_f32_16x16x32_f16(ah, bh[ni], acc[mi][ni], 0, 0, 0); \
        acc[mi][ni] = __builtin_amdgcn_mfma_f32_16x16x32_f16(ah, bl[ni], acc[mi][ni], 0, 0, 0); \
        acc[mi][ni] = __builtin_amdgcn_mfma_f32_16x16x32_f16(al, bh[ni], acc[mi][ni], 0, 0, 0); \
      }                                                                                 \
    }                                                                                   \
  }

  VQ_STAGE(0, 0);
  asm volatile("s_waitcnt vmcnt(0)" ::: "memory");
  __builtin_amdgcn_s_barrier();
  int cur = 0;
#pragma unroll 1
  for (int ks = 0; ks < 16; ++ks) {
    if (ks < 15) VQ_STAGE(cur ^ 1, (ks + 1) * 32);
    VQ_COMPUTE(cur);
    asm volatile("s_waitcnt vmcnt(0)" ::: "memory");
    __builtin_amdgcn_s_barrier();
    cur ^= 1;
  }

  float cnv[4];
#pragma unroll
  for (int ni = 0; ni < 4; ++ni) cnv[ni] = cn[n0 + wc * 64 + ni * 16 + lr];
#pragma unroll
  for (int mi = 0; mi < 4; ++mi)
#pragma unroll
    for (int j = 0; j < 4; ++j) {
      int m = m0 + wr * 64 + mi * 16 + lg * 4 + j;
      float zr = zn[m];
      float db = 3.4e38f; int jb = 0;
#pragma unroll
      for (int ni = 0; ni < 4; ++ni) {
        float dd = zr + cnv[ni] - 2.f * acc[mi][ni][j];
        int nn = n0 + wc * 64 + ni * 16 + lr;
        if (dd < db) { db = dd; jb = nn; }
      }
      unsigned long long key = ((unsigned long long)fkey(db) << 32) | (unsigned int)jb;
#pragma unroll
      for (int off = 8; off; off >>= 1) {
        unsigned long long o = __shfl_xor(key, off, 16);
        if (o < key) key = o;
      }
      if (lr == 0) atomicMin(best + m, key);
    }
#undef VQ_STAGE
#undef VQ_COMPUTE
}

// ===================== per-layer weight transpose+split =====================
__global__ __launch_bounds__(256) void wcvt_layer(const float* __restrict__ Wq,
    const float* __restrict__ Wk, const float* __restrict__ Wv, const float* __restrict__ Wo,
    const float* __restrict__ W1, const float* __restrict__ W2, u16* __restrict__ wt) {
  __shared__ float Ls[64][68];
  const int T = blockIdx.x, t = threadIdx.x;
  const float* src; u16 *dh, *dl; int K, N, kt, nt;
  if (T < 256) {
    int mat = T >> 6, tt = T & 63;
    src = (mat == 0) ? Wq : (mat == 1) ? Wk : (mat == 2) ? Wv : Wo;
    dh = wt + (size_t)mat * 524288; dl = dh + 262144;
    K = 512; N = 512; kt = tt >> 3; nt = tt & 7;
  } else if (T < 512) {
    int tt = T - 256; src = W1; dh = wt + 2097152; dl = dh + 1048576;
    K = 512; N = 2048; kt = tt >> 5; nt = tt & 31;
  } else {
    int tt = T - 512; src = W2; dh = wt + 4194304; dl = dh + 1048576;
    K = 2048; N = 512; kt = tt >> 3; nt = tt & 7;
  }
  const int k0 = kt * 64, n0 = nt * 64;
#pragma unroll
  for (int p = 0; p < 4; ++p) {
    int e = p * 256 + t;
    int kr = e >> 4, nc = (e & 15) * 4;
    *(float4*)&Ls[kr][nc] = *(const float4*)(src + (size_t)(k0 + kr) * N + n0 + nc);
  }
  __syncthreads();
  {
    int n = t >> 2, kc = (t & 3) * 16;
    unsigned hw[8], lw[8];
#pragma unroll
    for (int i = 0; i < 8; ++i) {
      u16 ha, la, hb, lb;
      splitf16(Ls[kc + 2 * i][n], ha, la);
      splitf16(Ls[kc + 2 * i + 1][n], hb, lb);
      hw[i] = (unsigned)ha | ((unsigned)hb << 16);
      lw[i] = (unsigned)la | ((unsigned)lb << 16);
    }
    size_t o = (size_t)(n0 + n) * K + k0 + kc;
    *(uint4*)&dh[o] = make_uint4(hw[0], hw[1], hw[2], hw[3]);
    *(uint4*)&dh[o + 8] = make_uint4(hw[4], hw[5], hw[6], hw[7]);
    *(uint4*)&dl[o] = make_uint4(lw[0], lw[1], lw[2], lw[3]);
    *(uint4*)&dl[o + 8] = make_uint4(lw[4], lw[5], lw[6], lw[7]);
  }
}

// ===================== row split to fp16 planes + row sumsq =====================
__global__ __launch_bounds__(128) void zcvt_kernel(const float* __restrict__ src,
    u16* __restrict__ hi, u16* __restrict__ lo, float* __restrict__ nrm) {
  __shared__ float red[2];
  const int row = blockIdx.x, t = threadIdx.x;
  const float4 a = *(const float4*)(src + (size_t)row * 512 + t * 4);
  u16 h0, h1, h2, h3, q0, q1, q2, q3;
  splitf16(a.x, h0, q0); splitf16(a.y, h1, q1); splitf16(a.z, h2, q2); splitf16(a.w, h3, q3);
  *(uint2*)&hi[(size_t)row * 512 + t * 4] = make_uint2((unsigned)h0 | ((unsigned)h1 << 16), (unsigned)h2 | ((unsigned)h3 << 16));
  *(uint2*)&lo[(size_t)row * 512 + t * 4] = make_uint2((unsigned)q0 | ((unsigned)q1 << 16), (unsigned)q2 | ((unsigned)q3 << 16));
  float s = a.x * a.x + a.y * a.y + a.z * a.z + a.w * a.w;
#pragma unroll
  for (int off = 32; off; off >>= 1) s += __shfl_xor(s, off, 64);
  if ((t & 63) == 0) red[t >> 6] = s;
  __syncthreads();
  if (t == 0) nrm[row] = red[0] + red[1];
}

// ======================= residual add + LayerNorm =======================
__global__ __launch_bounds__(128) void ln_kernel(const float* __restrict__ A,
    const float* __restrict__ Dl, const float* __restrict__ g,
    const float* __restrict__ bb, float* __restrict__ out) {
  __shared__ float red[2];
  const int row = blockIdx.x, t = threadIdx.x;
  const float4 a = *(const float4*)(A + (size_t)row * 512 + t * 4);
  const float4 d = *(const float4*)(Dl + (size_t)row * 512 + t * 4);
  float v0 = a.x + d.x, v1 = a.y + d.y, v2 = a.z + d.z, v3 = a.w + d.w;
  float s = v0 + v1 + v2 + v3;
#pragma unroll
  for (int off = 32; off; off >>= 1) s += __shfl_xor(s, off, 64);
  if ((t & 63) == 0) red[t >> 6] = s;
  __syncthreads();
  const float mu = (red[0] + red[1]) * (1.f / 512.f);
  const float w0 = v0 - mu, w1 = v1 - mu, w2 = v2 - mu, w3 = v3 - mu;
  float q = w0 * w0 + w1 * w1 + w2 * w2 + w3 * w3;
  __syncthreads();
#pragma unroll
  for (int off = 32; off; off >>= 1) q += __shfl_xor(q, off, 64);
  if ((t & 63) == 0) red[t >> 6] = q;
  __syncthreads();
  const float rs = rsqrtf((red[0] + red[1]) * (1.f / 512.f) + LN_EPS);
  const float4 gv = *(const float4*)(g + t * 4);
  const float4 bv = *(const float4*)(bb + t * 4);
  *(float4*)(out + (size_t)row * 512 + t * 4) =
      make_float4(w0 * rs * gv.x + bv.x, w1 * rs * gv.y + bv.y, w2 * rs * gv.z + bv.z, w3 * rs * gv.w + bv.w);
}

// ======================= gather zq, idx(as float), per-row loss, histogram =======================
__global__ __launch_bounds__(128) void gather_kernel(const unsigned long long* __restrict__ best,
    const float* __restrict__ Cb, const float* __restrict__ Ze, float* __restrict__ zq,
    float* __restrict__ oidx, float* __restrict__ rloss, int* __restrict__ hist) {
  __shared__ float red[2];
  const int row = blockIdx.x, t = threadIdx.x;
  const int idx = (int)(best[row] & 0xFFFFFFFFULL);
  const float4 c = *(const float4*)(Cb + (size_t)idx * 512 + t * 4);
  const float4 z = *(const float4*)(Ze + (size_t)row * 512 + t * 4);
  *(float4*)(zq + (size_t)row * 512 + t * 4) = c;
  const float d0 = c.x - z.x, d1 = c.y - z.y, d2 = c.z - z.z, d3 = c.w - z.w;
  float s = d0 * d0 + d1 * d1 + d2 * d2 + d3 * d3;
#pragma unroll
  for (int off = 32; off; off >>= 1) s += __shfl_xor(s, off, 64);
  if ((t & 63) == 0) red[t >> 6] = s;
  __syncthreads();
  if (t == 0) {
    rloss[row] = red[0] + red[1];
    oidx[row] = (float)idx;
    atomicAdd(hist + idx, 1);
  }
}

// ======================= finalize loss + perplexity =======================
__global__ __launch_bounds__(256) void fin_kernel(const float* __restrict__ rloss,
    const int* __restrict__ hist, float* __restrict__ oloss, float* __restrict__ oppl) {
  __shared__ float red[4];
  const int t = threadIdx.x;
  float s = 0.f;
  for (int i = t; i < 4096; i += 256) s += rloss[i];
#pragma unroll
  for (int off = 32; off; off >>= 1) s += __shfl_xor(s, off, 64);
  if ((t & 63) == 0) red[t >> 6] = s;
  __syncthreads();
  if (t == 0) oloss[0] = 0.25f * (red[0] + red[1] + red[2] + red[3]) * (1.f / 2097152.f);
  float e = 0.f;
  for (int i = t; i < KCB; i += 256) {
    float p = (float)hist[i] * (1.f / 4096.f);
    e += p * logf(p + 1e-10f);
  }
#pragma unroll
  for (int off = 32; off; off >>= 1) e += __shfl_xor(e, off, 64);
  __syncthreads();
  if ((t & 63) == 0) red[t >> 6] = e;
  __syncthreads();
  if (t == 0) oppl[0] = expf(-(red[0] + red[1] + red[2] + red[3]));
}

extern "C" void kernel_launch(void* const* d_in, const int* in_sizes, int n_in,
                              void* d_out, int out_size, void* d_ws, size_t ws_size,
                              hipStream_t stream) {
  const float* vec  = (const float*)d_in[0];
  const float* Wq   = (const float*)d_in[1];
  const float* bq   = (const float*)d_in[2];
  const float* Wk   = (const float*)d_in[3];
  const float* bk   = (const float*)d_in[4];
  const float* Wv   = (const float*)d_in[5];
  const float* bv   = (const float*)d_in[6];
  const float* Wo   = (const float*)d_in[7];
  const float* bo   = (const float*)d_in[8];
  const float* l1g  = (const float*)d_in[9];
  const float* l1b  = (const float*)d_in[10];
  const float* W1   = (const float*)d_in[11];
  const float* b1   = (const float*)d_in[12];
  const float* W2   = (const float*)d_in[13];
  const float* b2   = (const float*)d_in[14];
  const float* l2g  = (const float*)d_in[15];
  const float* l2b  = (const float*)d_in[16];
  const float* cb   = (const float*)d_in[17];

  char* wsb = (char*)d_ws;
  float* x   = (float*)(wsb + B_X);
  float* q   = (float*)(wsb + B_Q);
  float* k   = (float*)(wsb + B_K);
  float* v   = (float*)(wsb + B_V);
  float* ctx = (float*)(wsb + B_CT);
  float* tmp = (float*)(wsb + B_TMP);
  float* h   = (float*)(wsb + B_H);
  u16* cbh = (u16*)(wsb + B_CBH);
  u16* cbl = (u16*)(wsb + B_CBL);
  u16* zeh = (u16*)(wsb + B_ZEH);
  u16* zel = (u16*)(wsb + B_ZEL);
  float* zn = (float*)(wsb + B_ZN);
  float* cn = (float*)(wsb + B_CN);
  float* rl = (float*)(wsb + B_RL);
  unsigned long long* best = (unsigned long long*)(wsb + B_BEST);
  int* hist = (int*)(wsb + B_HIST);
  u16* wt = (u16*)(wsb + B_WT);
  u16* wto_h = wt + 1572864;      u16* wto_l = wt + 1835008;
  u16* wt1_h = wt + 2097152;      u16* wt1_l = wt + 3145728;
  u16* wt2_h = wt + 4194304;      u16* wt2_l = wt + 5242880;

  float* zq   = (float*)d_out;
  float* oidx = (float*)d_out + 2097152;
  float* olos = (float*)d_out + 2097152 + 4096;
  float* oppl = olos + 1;

  const dim3 gQkv(4, 64, 3);   // 64x128 tiles x {Q,K,V}
  const dim3 gProj(4, 64);     // 64x128 tiles
  const dim3 gFfn1(16, 32);    // 128x128 tiles
  const dim3 gAttn(4, 64);     // 128 q-rows x 64 bh

  for (int l = 0; l < NLAY; ++l) {
    const float* xin = l ? (const float*)x : vec;
    const size_t wo = (size_t)l * DDIM * DDIM;
    wcvt_layer<<<768, 256, 0, stream>>>(Wq + wo, Wk + wo, Wv + wo, Wo + wo,
        W1 + (size_t)l * DDIM * FFND, W2 + (size_t)l * FFND * DDIM, wt);
    qkv_enc<<<gQkv, 256, 0, stream>>>(xin, wt, bq + l * DDIM, bk + l * DDIM, bv + l * DDIM, q);
    attn_mfma<<<gAttn, 512, 0, stream>>>(q, k, v, ctx);
    gemm_enc<<<gProj, 256, 0, stream>>>(ctx, wto_h, wto_l, bo + l * DDIM, tmp, DDIM, DDIM);
    ln_kernel<<<MROWS, 128, 0, stream>>>(xin, tmp, l1g + l * DDIM, l1b + l * DDIM, x);
    gemm128<1><<<gFfn1, 256, 0, stream>>>(x, wt1_h, wt1_l, b1 + l * FFND, h, DDIM, FFND);
    gemm_enc<<<gProj, 256, 0, stream>>>(h, wt2_h, wt2_l, b2 + l * DDIM, tmp, FFND, DDIM);
    ln_kernel<<<MROWS, 128, 0, stream>>>(x, tmp, l2g + l * DDIM, l2b + l * DDIM, x);
  }

  zcvt_kernel<<<MROWS, 128, 0, stream>>>(x, zeh, zel, zn);
  zcvt_kernel<<<KCB, 128, 0, stream>>>(cb, cbh, cbl, cn);
  hipMemsetAsync(best, 0xFF, 4096 * 8, stream);
  hipMemsetAsync(hist, 0, KCB * 4, stream);
  vq256<<<1024, 1024, 0, stream>>>(zeh, zel, cbh, cbl, zn, cn, best);
  gather_kernel<<<MROWS, 128, 0, stream>>>(best, cb, x, zq, oidx, rl, hist);
  fin_kernel<<<1, 256, 0, stream>>>(rl, hist, olos, oppl);
}

// Round 14
// 901.637 us; speedup vs baseline: 1.1571x; 1.1452x over previous
//
#include <hip/hip_runtime.h>

#define MROWS 4096
#define DDIM  512
#define FFND  2048
#define NLAY  4
#define KCB   16384
#define LN_EPS 1e-5f

typedef unsigned short u16;
typedef _Float16 half8 __attribute__((ext_vector_type(8)));
typedef float f32x4 __attribute__((ext_vector_type(4)));

// ---- workspace layout (byte offsets) ----
#define B_X    0ULL
#define B_Q    8388608ULL
#define B_K    16777216ULL
#define B_V    25165824ULL
#define B_CT   33554432ULL
#define B_TMP  41943040ULL
#define B_H    8388608ULL
#define B_CBH  8388608ULL
#define B_CBL  25165824ULL
#define B_ZEH  41943040ULL
#define B_ZEL  46137344ULL
#define B_ZN   50331648ULL
#define B_CN   50348032ULL
#define B_RL   50413568ULL
#define B_BEST 50429952ULL
#define B_HIST 50462720ULL
#define B_WT   50528256ULL
#define B_TMP2 63111168ULL   /* after wt (12582912 B): second split-K partial */

// fp16 2-way split: x = h + l + eps, |eps| <= 2^-22|x|.
__device__ __forceinline__ void splitf16(float x, u16& h, u16& l) {
  _Float16 hh = (_Float16)x;          // RNE
  float r = x - (float)hh;            // exact
  _Float16 ll = (_Float16)r;          // RNE
  h = *(u16*)&hh; l = *(u16*)&ll;
}

__device__ __forceinline__ unsigned int fkey(float f) {
  unsigned int u = __float_as_uint(f);
  return (u & 0x80000000u) ? ~u : (u | 0x80000000u);
}

// ===================== 64x128 split-fp16 MFMA GEMM body (round-6/8 proven; qkv) =====================
template<int EPI>
__device__ __forceinline__ void gemm64_body(const float* __restrict__ Af,
    const u16* __restrict__ Bhi, const u16* __restrict__ Blo,
    const float* __restrict__ bias, float* __restrict__ C, int Kd, int N) {
  __shared__ __align__(16) u16 As[2][2048];   // 64 rows x 32 k
  __shared__ __align__(16) u16 Bs[2][4096];   // 128 rows x 32 k
  const int t = threadIdx.x;
  const int w = t >> 6, l = t & 63;
  const int lr = l & 15, lg = l >> 4;
  const int m0 = blockIdx.y * 64, n0 = blockIdx.x * 128;

  f32x4 acc[4][2];
  const f32x4 zf = {0.f, 0.f, 0.f, 0.f};
#pragma unroll
  for (int mi = 0; mi < 4; ++mi)
#pragma unroll
    for (int ni = 0; ni < 2; ++ni) acc[mi][ni] = zf;

  for (int k0 = 0; k0 < Kd; k0 += 32) {
#pragma unroll
    for (int pl = 0; pl < 2; ++pl) {
      const u16* gp = pl ? Blo : Bhi;
      u16* lb = &Bs[pl][0];
#pragma unroll
      for (int i = 0; i < 2; ++i) {
        int ob = w * 2048 + i * 1024;
        int o = ob + l * 16;
        int r = o >> 6;
        int pc = (o >> 4) & 3;
        int c = pc ^ ((r + (r >> 2)) & 3);
        const u16* g = gp + (size_t)(n0 + r) * Kd + k0 + c * 8;
        __builtin_amdgcn_global_load_lds(
            (const __attribute__((address_space(1))) unsigned int*)(const void*)g,
            (__attribute__((address_space(3))) unsigned int*)(void*)(lb + (ob >> 1)), 16, 0, 0);
      }
    }
#pragma unroll
    for (int p = 0; p < 2; ++p) {
      int e = p * 256 + t;
      int r = e >> 3, kc = (e & 7) * 4;
      float4 a = *(const float4*)(Af + (size_t)(m0 + r) * Kd + k0 + kc);
      u16 h0, h1, h2, h3, q0, q1, q2, q3;
      splitf16(a.x, h0, q0); splitf16(a.y, h1, q1); splitf16(a.z, h2, q2); splitf16(a.w, h3, q3);
      int idx = r * 32 + ((((kc >> 3) ^ ((r + (r >> 2)) & 3))) << 3) + (kc & 7);
      *(uint2*)&As[0][idx] = make_uint2((unsigned)h0 | ((unsigned)h1 << 16), (unsigned)h2 | ((unsigned)h3 << 16));
      *(uint2*)&As[1][idx] = make_uint2((unsigned)q0 | ((unsigned)q1 << 16), (unsigned)q2 | ((unsigned)q3 << 16));
    }
    __syncthreads();
    half8 ah[4], al[4], bh2[2], bl2[2];
#pragma unroll
    for (int mi = 0; mi < 4; ++mi) {
      int r = mi * 16 + lr;
      int idx = r * 32 + ((lg ^ ((r + (r >> 2)) & 3)) << 3);
      ah[mi] = *(const half8*)&As[0][idx];
      al[mi] = *(const half8*)&As[1][idx];
    }
#pragma unroll
    for (int ni = 0; ni < 2; ++ni) {
      int r = w * 32 + ni * 16 + lr;
      int idx = r * 32 + ((lg ^ ((r + (r >> 2)) & 3)) << 3);
      bh2[ni] = *(const half8*)&Bs[0][idx];
      bl2[ni] = *(const half8*)&Bs[1][idx];
    }
#pragma unroll
    for (int mi = 0; mi < 4; ++mi)
#pragma unroll
      for (int ni = 0; ni < 2; ++ni) {
        acc[mi][ni] = __builtin_amdgcn_mfma_f32_16x16x32_f16(ah[mi], bh2[ni], acc[mi][ni], 0, 0, 0);
        acc[mi][ni] = __builtin_amdgcn_mfma_f32_16x16x32_f16(ah[mi], bl2[ni], acc[mi][ni], 0, 0, 0);
        acc[mi][ni] = __builtin_amdgcn_mfma_f32_16x16x32_f16(al[mi], bh2[ni], acc[mi][ni], 0, 0, 0);
      }
    __syncthreads();
  }

  float bv[2];
#pragma unroll
  for (int ni = 0; ni < 2; ++ni) bv[ni] = bias[n0 + w * 32 + ni * 16 + lr];
#pragma unroll
  for (int mi = 0; mi < 4; ++mi)
#pragma unroll
    for (int j = 0; j < 4; ++j) {
      int m = m0 + mi * 16 + lg * 4 + j;
#pragma unroll
      for (int ni = 0; ni < 2; ++ni) {
        int n = n0 + w * 32 + ni * 16 + lr;
        float o = acc[mi][ni][j] + bv[ni];
        if (EPI == 1) o = fmaxf(o, 0.f);
        C[(size_t)m * N + n] = o;
      }
    }
}

__global__ __launch_bounds__(256) void qkv_enc(const float* __restrict__ Af,
    const u16* __restrict__ wt, const float* __restrict__ bq, const float* __restrict__ bk,
    const float* __restrict__ bv_, float* __restrict__ Cq) {
  const int z = blockIdx.z;
  const u16* Bhi = wt + (size_t)z * 524288;
  const u16* Blo = Bhi + 262144;
  const float* bias = (z == 0) ? bq : (z == 1) ? bk : bv_;
  float* C = Cq + (size_t)z * 2097152;
  gemm64_body<0>(Af, Bhi, Blo, bias, C, 512, 512);
}

// ===================== split-K 64x128 GEMM (Wo, FFN2): z=K-half, raw acc out =====================
__global__ __launch_bounds__(256) void gemm_splitk(const float* __restrict__ Af,
    const u16* __restrict__ Bhi, const u16* __restrict__ Blo,
    float* __restrict__ C0, float* __restrict__ C1, int Kd, int N) {
  __shared__ __align__(16) u16 As[2][2048];
  __shared__ __align__(16) u16 Bs[2][4096];
  const int t = threadIdx.x;
  const int w = t >> 6, l = t & 63;
  const int lr = l & 15, lg = l >> 4;
  const int m0 = blockIdx.y * 64, n0 = blockIdx.x * 128;
  const int z = blockIdx.z;
  const int koff = z * (Kd >> 1);
  const int kend = koff + (Kd >> 1);
  float* C = z ? C1 : C0;

  f32x4 acc[4][2];
  const f32x4 zf = {0.f, 0.f, 0.f, 0.f};
#pragma unroll
  for (int mi = 0; mi < 4; ++mi)
#pragma unroll
    for (int ni = 0; ni < 2; ++ni) acc[mi][ni] = zf;

  for (int k0 = koff; k0 < kend; k0 += 32) {
#pragma unroll
    for (int pl = 0; pl < 2; ++pl) {
      const u16* gp = pl ? Blo : Bhi;
      u16* lb = &Bs[pl][0];
#pragma unroll
      for (int i = 0; i < 2; ++i) {
        int ob = w * 2048 + i * 1024;
        int o = ob + l * 16;
        int r = o >> 6;
        int pc = (o >> 4) & 3;
        int c = pc ^ ((r + (r >> 2)) & 3);
        const u16* g = gp + (size_t)(n0 + r) * Kd + k0 + c * 8;
        __builtin_amdgcn_global_load_lds(
            (const __attribute__((address_space(1))) unsigned int*)(const void*)g,
            (__attribute__((address_space(3))) unsigned int*)(void*)(lb + (ob >> 1)), 16, 0, 0);
      }
    }
#pragma unroll
    for (int p = 0; p < 2; ++p) {
      int e = p * 256 + t;
      int r = e >> 3, kc = (e & 7) * 4;
      float4 a = *(const float4*)(Af + (size_t)(m0 + r) * Kd + k0 + kc);
      u16 h0, h1, h2, h3, q0, q1, q2, q3;
      splitf16(a.x, h0, q0); splitf16(a.y, h1, q1); splitf16(a.z, h2, q2); splitf16(a.w, h3, q3);
      int idx = r * 32 + ((((kc >> 3) ^ ((r + (r >> 2)) & 3))) << 3) + (kc & 7);
      *(uint2*)&As[0][idx] = make_uint2((unsigned)h0 | ((unsigned)h1 << 16), (unsigned)h2 | ((unsigned)h3 << 16));
      *(uint2*)&As[1][idx] = make_uint2((unsigned)q0 | ((unsigned)q1 << 16), (unsigned)q2 | ((unsigned)q3 << 16));
    }
    __syncthreads();
    half8 ah[4], al[4], bh2[2], bl2[2];
#pragma unroll
    for (int mi = 0; mi < 4; ++mi) {
      int r = mi * 16 + lr;
      int idx = r * 32 + ((lg ^ ((r + (r >> 2)) & 3)) << 3);
      ah[mi] = *(const half8*)&As[0][idx];
      al[mi] = *(const half8*)&As[1][idx];
    }
#pragma unroll
    for (int ni = 0; ni < 2; ++ni) {
      int r = w * 32 + ni * 16 + lr;
      int idx = r * 32 + ((lg ^ ((r + (r >> 2)) & 3)) << 3);
      bh2[ni] = *(const half8*)&Bs[0][idx];
      bl2[ni] = *(const half8*)&Bs[1][idx];
    }
#pragma unroll
    for (int mi = 0; mi < 4; ++mi)
#pragma unroll
      for (int ni = 0; ni < 2; ++ni) {
        acc[mi][ni] = __builtin_amdgcn_mfma_f32_16x16x32_f16(ah[mi], bh2[ni], acc[mi][ni], 0, 0, 0);
        acc[mi][ni] = __builtin_amdgcn_mfma_f32_16x16x32_f16(ah[mi], bl2[ni], acc[mi][ni], 0, 0, 0);
        acc[mi][ni] = __builtin_amdgcn_mfma_f32_16x16x32_f16(al[mi], bh2[ni], acc[mi][ni], 0, 0, 0);
      }
    __syncthreads();
  }

#pragma unroll
  for (int mi = 0; mi < 4; ++mi)
#pragma unroll
    for (int j = 0; j < 4; ++j) {
      int m = m0 + mi * 16 + lg * 4 + j;
#pragma unroll
      for (int ni = 0; ni < 2; ++ni) {
        int n = n0 + w * 32 + ni * 16 + lr;
        C[(size_t)m * N + n] = acc[mi][ni][j];
      }
    }
}

// ===================== 128x128 split-fp16 MFMA GEMM (FFN1) =====================
template<int EPI>
__global__ __launch_bounds__(256) void gemm128(const float* __restrict__ Af,
    const u16* __restrict__ Bhi, const u16* __restrict__ Blo,
    const float* __restrict__ bias, float* __restrict__ C, int Kd, int N) {
  __shared__ __align__(16) u16 As[2][4096];
  __shared__ __align__(16) u16 Bs[2][4096];
  const int t = threadIdx.x;
  const int w = t >> 6, l = t & 63;
  const int lr = l & 15, lg = l >> 4;
  const int wr = w >> 1, wc = w & 1;
  const int m0 = blockIdx.y * 128, n0 = blockIdx.x * 128;

  f32x4 acc[4][4];
  const f32x4 zf = {0.f, 0.f, 0.f, 0.f};
#pragma unroll
  for (int mi = 0; mi < 4; ++mi)
#pragma unroll
    for (int ni = 0; ni < 4; ++ni) acc[mi][ni] = zf;

  for (int k0 = 0; k0 < Kd; k0 += 32) {
#pragma unroll
    for (int pl = 0; pl < 2; ++pl) {
      const u16* gp = pl ? Blo : Bhi;
      u16* lb = &Bs[pl][0];
#pragma unroll
      for (int i = 0; i < 2; ++i) {
        int ob = (w * 2 + i) * 1024;
        int o = ob + l * 16;
        int r = o >> 6;
        int c = ((o >> 4) & 3) ^ ((r + (r >> 2)) & 3);
        const u16* g = gp + (size_t)(n0 + r) * Kd + k0 + c * 8;
        __builtin_amdgcn_global_load_lds(
            (const __attribute__((address_space(1))) unsigned int*)(const void*)g,
            (__attribute__((address_space(3))) unsigned int*)(void*)(lb + (ob >> 1)), 16, 0, 0);
      }
    }
#pragma unroll
    for (int p = 0; p < 4; ++p) {
      int e = p * 256 + t;
      int r = e >> 3, kc = (e & 7) * 4;
      float4 a = *(const float4*)(Af + (size_t)(m0 + r) * Kd + k0 + kc);
      u16 h0, h1, h2, h3, q0, q1, q2, q3;
      splitf16(a.x, h0, q0); splitf16(a.y, h1, q1); splitf16(a.z, h2, q2); splitf16(a.w, h3, q3);
      int idx = r * 32 + ((((kc >> 3) ^ ((r + (r >> 2)) & 3))) << 3) + (kc & 7);
      *(uint2*)&As[0][idx] = make_uint2((unsigned)h0 | ((unsigned)h1 << 16), (unsigned)h2 | ((unsigned)h3 << 16));
      *(uint2*)&As[1][idx] = make_uint2((unsigned)q0 | ((unsigned)q1 << 16), (unsigned)q2 | ((unsigned)q3 << 16));
    }
    __syncthreads();
    half8 ah[4], al[4], bh4[4], bl4[4];
#pragma unroll
    for (int mi = 0; mi < 4; ++mi) {
      int r = wr * 64 + mi * 16 + lr;
      int idx = r * 32 + ((lg ^ ((r + (r >> 2)) & 3)) << 3);
      ah[mi] = *(const half8*)&As[0][idx];
      al[mi] = *(const half8*)&As[1][idx];
    }
#pragma unroll
    for (int ni = 0; ni < 4; ++ni) {
      int r = wc * 64 + ni * 16 + lr;
      int idx = r * 32 + ((lg ^ ((r + (r >> 2)) & 3)) << 3);
      bh4[ni] = *(const half8*)&Bs[0][idx];
      bl4[ni] = *(const half8*)&Bs[1][idx];
    }
#pragma unroll
    for (int mi = 0; mi < 4; ++mi)
#pragma unroll
      for (int ni = 0; ni < 4; ++ni) {
        acc[mi][ni] = __builtin_amdgcn_mfma_f32_16x16x32_f16(ah[mi], bh4[ni], acc[mi][ni], 0, 0, 0);
        acc[mi][ni] = __builtin_amdgcn_mfma_f32_16x16x32_f16(ah[mi], bl4[ni], acc[mi][ni], 0, 0, 0);
        acc[mi][ni] = __builtin_amdgcn_mfma_f32_16x16x32_f16(al[mi], bh4[ni], acc[mi][ni], 0, 0, 0);
      }
    __syncthreads();
  }

  float bv[4];
#pragma unroll
  for (int ni = 0; ni < 4; ++ni) bv[ni] = bias[n0 + wc * 64 + ni * 16 + lr];
#pragma unroll
  for (int mi = 0; mi < 4; ++mi)
#pragma unroll
    for (int j = 0; j < 4; ++j) {
      int m = m0 + wr * 64 + mi * 16 + lg * 4 + j;
#pragma unroll
      for (int ni = 0; ni < 4; ++ni) {
        int n = n0 + wc * 64 + ni * 16 + lr;
        float o = acc[mi][ni][j] + bv[ni];
        if (EPI == 1) o = fmaxf(o, 0.f);
        C[(size_t)m * N + n] = o;
      }
    }
}

// ===================== MFMA flash attention (T14 async-stage, round-13 proven) =====================
__global__ __launch_bounds__(512) void attn_mfma(const float* __restrict__ Q,
    const float* __restrict__ Kx, const float* __restrict__ V, float* __restrict__ O) {
  __shared__ __align__(16) u16 Ks[2][4608];   // [64 key][72]
  __shared__ __align__(16) u16 Ps[2][9216];   // [128 q][72]
  __shared__ __align__(16) u16 Vt[2][4608];   // [64 d][72]
  const int t = threadIdx.x;
  const int w = t >> 6, l = t & 63;
  const int lr = l & 15, lg = l >> 4;
  const int bh = blockIdx.y;
  const int q0 = blockIdx.x * 128;
  const float* Qb = Q + ((size_t)bh * 512 + q0) * 64;
  const float* Kb = Kx + (size_t)bh * 512 * 64;
  const float* Vb = V + (size_t)bh * 512 * 64;

  const int srow = t >> 4, sc4 = (t & 15) * 4;

  half8 qh[2], qlo[2];
#pragma unroll
  for (int ks = 0; ks < 2; ++ks) {
    const float* p = Qb + (size_t)(w * 16 + lr) * 64 + ks * 32 + lg * 8;
    float4 f0 = *(const float4*)p;
    float4 f1 = *(const float4*)(p + 4);
    float v8[8] = {f0.x, f0.y, f0.z, f0.w, f1.x, f1.y, f1.z, f1.w};
#pragma unroll
    for (int j = 0; j < 8; ++j) {
      _Float16 hh = (_Float16)v8[j];
      float r = v8[j] - (float)hh;
      qh[ks][j] = hh;
      qlo[ks][j] = (_Float16)r;
    }
  }

  float mrun[4] = {-1e30f, -1e30f, -1e30f, -1e30f};
  float lrun[4] = {0.f, 0.f, 0.f, 0.f};
  f32x4 o[4];
  const f32x4 zf = {0.f, 0.f, 0.f, 0.f};
#pragma unroll
  for (int dn = 0; dn < 4; ++dn) o[dn] = zf;

  float4 kreg[2], vreg[2];
#pragma unroll
  for (int i = 0; i < 2; ++i) {
    int row = i * 32 + srow;
    kreg[i] = *(const float4*)(Kb + (size_t)row * 64 + sc4);
    vreg[i] = *(const float4*)(Vb + (size_t)row * 64 + sc4);
  }

#pragma unroll 1
  for (int kc = 0; kc < 8; ++kc) {
    __syncthreads();
#pragma unroll
    for (int i = 0; i < 2; ++i) {
      int row = i * 32 + srow;
      u16 h0, h1, h2, h3, l0, l1, l2, l3;
      splitf16(kreg[i].x, h0, l0); splitf16(kreg[i].y, h1, l1);
      splitf16(kreg[i].z, h2, l2); splitf16(kreg[i].w, h3, l3);
      *(uint2*)&Ks[0][row * 72 + sc4] = make_uint2((unsigned)h0 | ((unsigned)h1 << 16), (unsigned)h2 | ((unsigned)h3 << 16));
      *(uint2*)&Ks[1][row * 72 + sc4] = make_uint2((unsigned)l0 | ((unsigned)l1 << 16), (unsigned)l2 | ((unsigned)l3 << 16));
      u16 vh[4], vl[4];
      splitf16(vreg[i].x, vh[0], vl[0]); splitf16(vreg[i].y, vh[1], vl[1]);
      splitf16(vreg[i].z, vh[2], vl[2]); splitf16(vreg[i].w, vh[3], vl[3]);
#pragma unroll
      for (int ii = 0; ii < 4; ++ii) {
        Vt[0][(sc4 + ii) * 72 + row] = vh[ii];
        Vt[1][(sc4 + ii) * 72 + row] = vl[ii];
      }
    }
    __syncthreads();
    if (kc < 7) {
#pragma unroll
      for (int i = 0; i < 2; ++i) {
        int row = i * 32 + srow;
        kreg[i] = *(const float4*)(Kb + (size_t)((kc + 1) * 64 + row) * 64 + sc4);
        vreg[i] = *(const float4*)(Vb + (size_t)((kc + 1) * 64 + row) * 64 + sc4);
      }
    }
    f32x4 sa[4];
#pragma unroll
    for (int ni = 0; ni < 4; ++ni) sa[ni] = zf;
    __builtin_amdgcn_s_setprio(1);
#pragma unroll
    for (int ks = 0; ks < 2; ++ks) {
#pragma unroll
      for (int ni = 0; ni < 4; ++ni) {
        half8 kh = *(const half8*)&Ks[0][(ni * 16 + lr) * 72 + ks * 32 + lg * 8];
        half8 klo = *(const half8*)&Ks[1][(ni * 16 + lr) * 72 + ks * 32 + lg * 8];
        sa[ni] = __builtin_amdgcn_mfma_f32_16x16x32_f16(qh[ks], kh, sa[ni], 0, 0, 0);
        sa[ni] = __builtin_amdgcn_mfma_f32_16x16x32_f16(qh[ks], klo, sa[ni], 0, 0, 0);
        sa[ni] = __builtin_amdgcn_mfma_f32_16x16x32_f16(qlo[ks], kh, sa[ni], 0, 0, 0);
      }
    }
    __builtin_amdgcn_s_setprio(0);
#pragma unroll
    for (int j = 0; j < 4; ++j) {
      float sv[4];
#pragma unroll
      for (int ni = 0; ni < 4; ++ni) sv[ni] = sa[ni][j] * 8.f;
      float mx = fmaxf(fmaxf(sv[0], sv[1]), fmaxf(sv[2], sv[3]));
#pragma unroll
      for (int off = 8; off; off >>= 1) mx = fmaxf(mx, __shfl_xor(mx, off, 16));
      float mnew = fmaxf(mrun[j], mx);
      float fac = expf(mrun[j] - mnew);
      float ps = 0.f;
#pragma unroll
      for (int ni = 0; ni < 4; ++ni) {
        float p = expf(sv[ni] - mnew);
        ps += p;
        u16 ph_, pl_;
        splitf16(p, ph_, pl_);
        Ps[0][(w * 16 + lg * 4 + j) * 72 + ni * 16 + lr] = ph_;
        Ps[1][(w * 16 + lg * 4 + j) * 72 + ni * 16 + lr] = pl_;
      }
#pragma unroll
      for (int off = 8; off; off >>= 1) ps += __shfl_xor(ps, off, 16);
      lrun[j] = lrun[j] * fac + ps;
      mrun[j] = mnew;
#pragma unroll
      for (int dn = 0; dn < 4; ++dn) o[dn][j] *= fac;
    }
    __builtin_amdgcn_s_setprio(1);
#pragma unroll
    for (int ks = 0; ks < 2; ++ks) {
      half8 ph8 = *(const half8*)&Ps[0][(w * 16 + lr) * 72 + ks * 32 + lg * 8];
      half8 pl8 = *(const half8*)&Ps[1][(w * 16 + lr) * 72 + ks * 32 + lg * 8];
#pragma unroll
      for (int dn = 0; dn < 4; ++dn) {
        half8 vh8 = *(const half8*)&Vt[0][(dn * 16 + lr) * 72 + ks * 32 + lg * 8];
        half8 vl8 = *(const half8*)&Vt[1][(dn * 16 + lr) * 72 + ks * 32 + lg * 8];
        o[dn] = __builtin_amdgcn_mfma_f32_16x16x32_f16(ph8, vh8, o[dn], 0, 0, 0);
        o[dn] = __builtin_amdgcn_mfma_f32_16x16x32_f16(ph8, vl8, o[dn], 0, 0, 0);
        o[dn] = __builtin_amdgcn_mfma_f32_16x16x32_f16(pl8, vh8, o[dn], 0, 0, 0);
      }
    }
    __builtin_amdgcn_s_setprio(0);
  }
  float inv[4];
#pragma unroll
  for (int j = 0; j < 4; ++j) inv[j] = 1.f / lrun[j];
  float* Ob = O + ((size_t)bh * 512 + q0) * 64;
#pragma unroll
  for (int dn = 0; dn < 4; ++dn)
#pragma unroll
    for (int j = 0; j < 4; ++j)
      Ob[(size_t)(w * 16 + lg * 4 + j) * 64 + dn * 16 + lr] = o[dn][j] * inv[j];
}

// ===================== VQ 256x256, 16 waves, L2-locality block order (round-11 proven) =====================
__global__ __launch_bounds__(1024) void vq256(
    const u16* __restrict__ Ahi, const u16* __restrict__ Alo,
    const u16* __restrict__ Bhi, const u16* __restrict__ Blo,
    const float* __restrict__ zn, const float* __restrict__ cn,
    unsigned long long* __restrict__ best) {
  __shared__ __align__(16) u16 As[2][2][8192];
  __shared__ __align__(16) u16 Bs[2][2][8192];
  const int t = threadIdx.x;
  const int w = t >> 6, l = t & 63;
  const int lr = l & 15, lg = l >> 4;
  const int wr = w >> 2, wc = w & 3;
  const int f = blockIdx.x;
  const int xcd = f & 7, pos = f >> 3;
  const int ml = pos & 15;
  const int nl = pos >> 4;
  const int n0 = (xcd * 8 + nl) * 256;
  const int m0 = ml * 256;

  f32x4 acc[4][4];
  const f32x4 zf = {0.f, 0.f, 0.f, 0.f};
#pragma unroll
  for (int mi = 0; mi < 4; ++mi)
#pragma unroll
    for (int ni = 0; ni < 4; ++ni) acc[mi][ni] = zf;

  const int s_ob = w * 1024;
  int s_r, s_c;
  {
    int o = s_ob + l * 16;
    s_r = o >> 6;
    s_c = ((o >> 4) & 3) ^ ((s_r + (s_r >> 2)) & 3);
  }

#define VQ_STAGE(buf, k0)                                                               \
  {                                                                                     \
    size_t ea = (size_t)(m0 + s_r) * 512 + (k0) + s_c * 8;                              \
    size_t eb = (size_t)(n0 + s_r) * 512 + (k0) + s_c * 8;                              \
    __builtin_amdgcn_global_load_lds(                                                   \
        (const __attribute__((address_space(1))) unsigned int*)(const void*)(Ahi + ea), \
        (__attribute__((address_space(3))) unsigned int*)(void*)(&As[buf][0][s_ob >> 1]), 16, 0, 0); \
    __builtin_amdgcn_global_load_lds(                                                   \
        (const __attribute__((address_space(1))) unsigned int*)(const void*)(Alo + ea), \
        (__attribute__((address_space(3))) unsigned int*)(void*)(&As[buf][1][s_ob >> 1]), 16, 0, 0); \
    __builtin_amdgcn_global_load_lds(                                                   \
        (const __attribute__((address_space(1))) unsigned int*)(const void*)(Bhi + eb), \
        (__attribute__((address_space(3))) unsigned int*)(void*)(&Bs[buf][0][s_ob >> 1]), 16, 0, 0); \
    __builtin_amdgcn_global_load_lds(                                                   \
        (const __attribute__((address_space(1))) unsigned int*)(const void*)(Blo + eb), \
        (__attribute__((address_space(3))) unsigned int*)(void*)(&Bs[buf][1][s_ob >> 1]), 16, 0, 0); \
  }

#define VQ_COMPUTE(buf)                                                                 \
  {                                                                                     \
    half8 bh[4], bl[4];                                                                 \
    _Pragma("unroll")                                                                   \
    for (int ni = 0; ni < 4; ++ni) {                                                    \
      int r = wc * 64 + ni * 16 + lr;                                                   \
      int idx = r * 32 + ((lg ^ ((r + (r >> 2)) & 3)) << 3);                            \
      bh[ni] = *(const half8*)&Bs[buf][0][idx];                                         \
      bl[ni] = *(const half8*)&Bs[buf][1][idx];                                         \
    }                                                                                   \
    _Pragma("unroll")                                                                   \
    for (int mi = 0; mi < 4; ++mi) {                                                    \
      int r = wr * 64 + mi * 16 + lr;                                                   \
      int idx = r * 32 + ((lg ^ ((r + (r >> 2)) & 3)) << 3);                            \
      half8 ah = *(const half8*)&As[buf][0][idx];                                       \
      half8 al = *(const half8*)&As[buf][1][idx];                                       \
      _Pragma("unroll")                                                                 \
      for (int ni = 0; ni < 4; ++ni) {                                                  \
        acc[mi][ni] = __builtin_amdgcn_mfma_f32_16x16x32_f16(ah, bh[ni], acc[mi][ni], 0, 0, 0); \
        acc[mi][ni] = __builtin_amdgcn_mfma_f32_16x16x32_f16(ah, bl[ni], acc[mi][ni], 0, 0, 0); \
        acc[mi][ni] = __builtin_amdgcn_mfma_f32_16x16x32_f16(al, bh[ni], acc[mi][ni], 0, 0, 0); \
      }                                                                                 \
    }                                                                                   \
  }

  VQ_STAGE(0, 0);
  asm volatile("s_waitcnt vmcnt(0)" ::: "memory");
  __builtin_amdgcn_s_barrier();
  int cur = 0;
#pragma unroll 1
  for (int ks = 0; ks < 16; ++ks) {
    if (ks < 15) VQ_STAGE(cur ^ 1, (ks + 1) * 32);
    VQ_COMPUTE(cur);
    asm volatile("s_waitcnt vmcnt(0)" ::: "memory");
    __builtin_amdgcn_s_barrier();
    cur ^= 1;
  }

  float cnv[4];
#pragma unroll
  for (int ni = 0; ni < 4; ++ni) cnv[ni] = cn[n0 + wc * 64 + ni * 16 + lr];
#pragma unroll
  for (int mi = 0; mi < 4; ++mi)
#pragma unroll
    for (int j = 0; j < 4; ++j) {
      int m = m0 + wr * 64 + mi * 16 + lg * 4 + j;
      float zr = zn[m];
      float db = 3.4e38f; int jb = 0;
#pragma unroll
      for (int ni = 0; ni < 4; ++ni) {
        float dd = zr + cnv[ni] - 2.f * acc[mi][ni][j];
        int nn = n0 + wc * 64 + ni * 16 + lr;
        if (dd < db) { db = dd; jb = nn; }
      }
      unsigned long long key = ((unsigned long long)fkey(db) << 32) | (unsigned int)jb;
#pragma unroll
      for (int off = 8; off; off >>= 1) {
        unsigned long long o = __shfl_xor(key, off, 16);
        if (o < key) key = o;
      }
      if (lr == 0) atomicMin(best + m, key);
    }
#undef VQ_STAGE
#undef VQ_COMPUTE
}

// ===================== per-layer weight transpose+split =====================
__global__ __launch_bounds__(256) void wcvt_layer(const float* __restrict__ Wq,
    const float* __restrict__ Wk, const float* __restrict__ Wv, const float* __restrict__ Wo,
    const float* __restrict__ W1, const float* __restrict__ W2, u16* __restrict__ wt) {
  __shared__ float Ls[64][68];
  const int T = blockIdx.x, t = threadIdx.x;
  const float* src; u16 *dh, *dl; int K, N, kt, nt;
  if (T < 256) {
    int mat = T >> 6, tt = T & 63;
    src = (mat == 0) ? Wq : (mat == 1) ? Wk : (mat == 2) ? Wv : Wo;
    dh = wt + (size_t)mat * 524288; dl = dh + 262144;
    K = 512; N = 512; kt = tt >> 3; nt = tt & 7;
  } else if (T < 512) {
    int tt = T - 256; src = W1; dh = wt + 2097152; dl = dh + 1048576;
    K = 512; N = 2048; kt = tt >> 5; nt = tt & 31;
  } else {
    int tt = T - 512; src = W2; dh = wt + 4194304; dl = dh + 1048576;
    K = 2048; N = 512; kt = tt >> 3; nt = tt & 7;
  }
  const int k0 = kt * 64, n0 = nt * 64;
#pragma unroll
  for (int p = 0; p < 4; ++p) {
    int e = p * 256 + t;
    int kr = e >> 4, nc = (e & 15) * 4;
    *(float4*)&Ls[kr][nc] = *(const float4*)(src + (size_t)(k0 + kr) * N + n0 + nc);
  }
  __syncthreads();
  {
    int n = t >> 2, kc = (t & 3) * 16;
    unsigned hw[8], lw[8];
#pragma unroll
    for (int i = 0; i < 8; ++i) {
      u16 ha, la, hb, lb;
      splitf16(Ls[kc + 2 * i][n], ha, la);
      splitf16(Ls[kc + 2 * i + 1][n], hb, lb);
      hw[i] = (unsigned)ha | ((unsigned)hb << 16);
      lw[i] = (unsigned)la | ((unsigned)lb << 16);
    }
    size_t o = (size_t)(n0 + n) * K + k0 + kc;
    *(uint4*)&dh[o] = make_uint4(hw[0], hw[1], hw[2], hw[3]);
    *(uint4*)&dh[o + 8] = make_uint4(hw[4], hw[5], hw[6], hw[7]);
    *(uint4*)&dl[o] = make_uint4(lw[0], lw[1], lw[2], lw[3]);
    *(uint4*)&dl[o + 8] = make_uint4(lw[4], lw[5], lw[6], lw[7]);
  }
}

// ===================== row split to fp16 planes + row sumsq =====================
__global__ __launch_bounds__(128) void zcvt_kernel(const float* __restrict__ src,
    u16* __restrict__ hi, u16* __restrict__ lo, float* __restrict__ nrm) {
  __shared__ float red[2];
  const int row = blockIdx.x, t = threadIdx.x;
  const float4 a = *(const float4*)(src + (size_t)row * 512 + t * 4);
  u16 h0, h1, h2, h3, q0, q1, q2, q3;
  splitf16(a.x, h0, q0); splitf16(a.y, h1, q1); splitf16(a.z, h2, q2); splitf16(a.w, h3, q3);
  *(uint2*)&hi[(size_t)row * 512 + t * 4] = make_uint2((unsigned)h0 | ((unsigned)h1 << 16), (unsigned)h2 | ((unsigned)h3 << 16));
  *(uint2*)&lo[(size_t)row * 512 + t * 4] = make_uint2((unsigned)q0 | ((unsigned)q1 << 16), (unsigned)q2 | ((unsigned)q3 << 16));
  float s = a.x * a.x + a.y * a.y + a.z * a.z + a.w * a.w;
#pragma unroll
  for (int off = 32; off; off >>= 1) s += __shfl_xor(s, off, 64);
  if ((t & 63) == 0) red[t >> 6] = s;
  __syncthreads();
  if (t == 0) nrm[row] = red[0] + red[1];
}

// ======================= residual + split-K partials + bias + LayerNorm =======================
__global__ __launch_bounds__(128) void ln3_kernel(const float* __restrict__ A,
    const float* __restrict__ D1, const float* __restrict__ D2, const float* __restrict__ gb,
    const float* __restrict__ g, const float* __restrict__ bb, float* __restrict__ out) {
  __shared__ float red[2];
  const int row = blockIdx.x, t = threadIdx.x;
  const float4 a  = *(const float4*)(A  + (size_t)row * 512 + t * 4);
  const float4 d1 = *(const float4*)(D1 + (size_t)row * 512 + t * 4);
  const float4 d2 = *(const float4*)(D2 + (size_t)row * 512 + t * 4);
  const float4 gv2 = *(const float4*)(gb + t * 4);
  float v0 = a.x + d1.x + d2.x + gv2.x, v1 = a.y + d1.y + d2.y + gv2.y;
  float v2 = a.z + d1.z + d2.z + gv2.z, v3 = a.w + d1.w + d2.w + gv2.w;
  float s = v0 + v1 + v2 + v3;
#pragma unroll
  for (int off = 32; off; off >>= 1) s += __shfl_xor(s, off, 64);
  if ((t & 63) == 0) red[t >> 6] = s;
  __syncthreads();
  const float mu = (red[0] + red[1]) * (1.f / 512.f);
  const float w0 = v0 - mu, w1 = v1 - mu, w2 = v2 - mu, w3 = v3 - mu;
  float q = w0 * w0 + w1 * w1 + w2 * w2 + w3 * w3;
  __syncthreads();
#pragma unroll
  for (int off = 32; off; off >>= 1) q += __shfl_xor(q, off, 64);
  if ((t & 63) == 0) red[t >> 6] = q;
  __syncthreads();
  const float rs = rsqrtf((red[0] + red[1]) * (1.f / 512.f) + LN_EPS);
  const float4 gv = *(const float4*)(g + t * 4);
  const float4 bv = *(const float4*)(bb + t * 4);
  *(float4*)(out + (size_t)row * 512 + t * 4) =
      make_float4(w0 * rs * gv.x + bv.x, w1 * rs * gv.y + bv.y, w2 * rs * gv.z + bv.z, w3 * rs * gv.w + bv.w);
}

// ======================= gather zq, idx(as float), per-row loss, histogram =======================
__global__ __launch_bounds__(128) void gather_kernel(const unsigned long long* __restrict__ best,
    const float* __restrict__ Cb, const float* __restrict__ Ze, float* __restrict__ zq,
    float* __restrict__ oidx, float* __restrict__ rloss, int* __restrict__ hist) {
  __shared__ float red[2];
  const int row = blockIdx.x, t = threadIdx.x;
  const int idx = (int)(best[row] & 0xFFFFFFFFULL);
  const float4 c = *(const float4*)(Cb + (size_t)idx * 512 + t * 4);
  const float4 z = *(const float4*)(Ze + (size_t)row * 512 + t * 4);
  *(float4*)(zq + (size_t)row * 512 + t * 4) = c;
  const float d0 = c.x - z.x, d1 = c.y - z.y, d2 = c.z - z.z, d3 = c.w - z.w;
  float s = d0 * d0 + d1 * d1 + d2 * d2 + d3 * d3;
#pragma unroll
  for (int off = 32; off; off >>= 1) s += __shfl_xor(s, off, 64);
  if ((t & 63) == 0) red[t >> 6] = s;
  __syncthreads();
  if (t == 0) {
    rloss[row] = red[0] + red[1];
    oidx[row] = (float)idx;
    atomicAdd(hist + idx, 1);
  }
}

// ======================= finalize loss + perplexity =======================
__global__ __launch_bounds__(256) void fin_kernel(const float* __restrict__ rloss,
    const int* __restrict__ hist, float* __restrict__ oloss, float* __restrict__ oppl) {
  __shared__ float red[4];
  const int t = threadIdx.x;
  float s = 0.f;
  for (int i = t; i < 4096; i += 256) s += rloss[i];
#pragma unroll
  for (int off = 32; off; off >>= 1) s += __shfl_xor(s, off, 64);
  if ((t & 63) == 0) red[t >> 6] = s;
  __syncthreads();
  if (t == 0) oloss[0] = 0.25f * (red[0] + red[1] + red[2] + red[3]) * (1.f / 2097152.f);
  float e = 0.f;
  for (int i = t; i < KCB; i += 256) {
    float p = (float)hist[i] * (1.f / 4096.f);
    e += p * logf(p + 1e-10f);
  }
#pragma unroll
  for (int off = 32; off; off >>= 1) e += __shfl_xor(e, off, 64);
  __syncthreads();
  if ((t & 63) == 0) red[t >> 6] = e;
  __syncthreads();
  if (t == 0) oppl[0] = expf(-(red[0] + red[1] + red[2] + red[3]));
}

extern "C" void kernel_launch(void* const* d_in, const int* in_sizes, int n_in,
                              void* d_out, int out_size, void* d_ws, size_t ws_size,
                              hipStream_t stream) {
  const float* vec  = (const float*)d_in[0];
  const float* Wq   = (const float*)d_in[1];
  const float* bq   = (const float*)d_in[2];
  const float* Wk   = (const float*)d_in[3];
  const float* bk   = (const float*)d_in[4];
  const float* Wv   = (const float*)d_in[5];
  const float* bv   = (const float*)d_in[6];
  const float* Wo   = (const float*)d_in[7];
  const float* bo   = (const float*)d_in[8];
  const float* l1g  = (const float*)d_in[9];
  const float* l1b  = (const float*)d_in[10];
  const float* W1   = (const float*)d_in[11];
  const float* b1   = (const float*)d_in[12];
  const float* W2   = (const float*)d_in[13];
  const float* b2   = (const float*)d_in[14];
  const float* l2g  = (const float*)d_in[15];
  const float* l2b  = (const float*)d_in[16];
  const float* cb   = (const float*)d_in[17];

  char* wsb = (char*)d_ws;
  float* x    = (float*)(wsb + B_X);
  float* q    = (float*)(wsb + B_Q);
  float* k    = (float*)(wsb + B_K);
  float* v    = (float*)(wsb + B_V);
  float* ctx  = (float*)(wsb + B_CT);
  float* tmp  = (float*)(wsb + B_TMP);
  float* tmp2 = (float*)(wsb + B_TMP2);
  float* h    = (float*)(wsb + B_H);
  u16* cbh = (u16*)(wsb + B_CBH);
  u16* cbl = (u16*)(wsb + B_CBL);
  u16* zeh = (u16*)(wsb + B_ZEH);
  u16* zel = (u16*)(wsb + B_ZEL);
  float* zn = (float*)(wsb + B_ZN);
  float* cn = (float*)(wsb + B_CN);
  float* rl = (float*)(wsb + B_RL);
  unsigned long long* best = (unsigned long long*)(wsb + B_BEST);
  int* hist = (int*)(wsb + B_HIST);
  u16* wt = (u16*)(wsb + B_WT);
  u16* wto_h = wt + 1572864;      u16* wto_l = wt + 1835008;
  u16* wt1_h = wt + 2097152;      u16* wt1_l = wt + 3145728;
  u16* wt2_h = wt + 4194304;      u16* wt2_l = wt + 5242880;

  float* zq   = (float*)d_out;
  float* oidx = (float*)d_out + 2097152;
  float* olos = (float*)d_out + 2097152 + 4096;
  float* oppl = olos + 1;

  const dim3 gQkv(4, 64, 3);    // 64x128 tiles x {Q,K,V}
  const dim3 gSplit(4, 64, 2);  // 64x128 tiles x 2 K-halves (Wo, FFN2)
  const dim3 gFfn1(16, 32);     // 128x128 tiles
  const dim3 gAttn(4, 64);      // 128 q-rows x 64 bh

  for (int l = 0; l < NLAY; ++l) {
    const float* xin = l ? (const float*)x : vec;
    const size_t wo = (size_t)l * DDIM * DDIM;
    wcvt_layer<<<768, 256, 0, stream>>>(Wq + wo, Wk + wo, Wv + wo, Wo + wo,
        W1 + (size_t)l * DDIM * FFND, W2 + (size_t)l * FFND * DDIM, wt);
    qkv_enc<<<gQkv, 256, 0, stream>>>(xin, wt, bq + l * DDIM, bk + l * DDIM, bv + l * DDIM, q);
    attn_mfma<<<gAttn, 512, 0, stream>>>(q, k, v, ctx);
    gemm_splitk<<<gSplit, 256, 0, stream>>>(ctx, wto_h, wto_l, tmp, tmp2, DDIM, DDIM);
    ln3_kernel<<<MROWS, 128, 0, stream>>>(xin, tmp, tmp2, bo + l * DDIM,
        l1g + l * DDIM, l1b + l * DDIM, x);
    gemm128<1><<<gFfn1, 256, 0, stream>>>(x, wt1_h, wt1_l, b1 + l * FFND, h, DDIM, FFND);
    gemm_splitk<<<gSplit, 256, 0, stream>>>(h, wt2_h, wt2_l, tmp, tmp2, FFND, DDIM);
    ln3_kernel<<<MROWS, 128, 0, stream>>>(x, tmp, tmp2, b2 + l * DDIM,
        l2g + l * DDIM, l2b + l * DDIM, x);
  }

  zcvt_kernel<<<MROWS, 128, 0, stream>>>(x, zeh, zel, zn);
  zcvt_kernel<<<KCB, 128, 0, stream>>>(cb, cbh, cbl, cn);
  hipMemsetAsync(best, 0xFF, 4096 * 8, stream);
  hipMemsetAsync(hist, 0, KCB * 4, stream);
  vq256<<<1024, 1024, 0, stream>>>(zeh, zel, cbh, cbl, zn, cn, best);
  gather_kernel<<<MROWS, 128, 0, stream>>>(best, cb, x, zq, oidx, rl, hist);
  fin_kernel<<<1, 256, 0, stream>>>(rl, hist, olos, oppl);
}